// Round 1
// baseline (750.765 us; speedup 1.0000x reference)
//
#include <hip/hip_runtime.h>
#include <hip/hip_bf16.h>

#define HDIM 128

typedef unsigned short u16;
typedef unsigned int u32;

__device__ __forceinline__ float bf2f(u16 u) {
  union { u32 i; float f; } x; x.i = ((u32)u) << 16; return x.f;
}
__device__ __forceinline__ u16 f2bf(float f) {
  union { float f; u32 i; } x; x.f = f;
  u32 r = x.i + 0x7fffu + ((x.i >> 16) & 1u);
  return (u16)(r >> 16);
}

__global__ __launch_bounds__(256) void k_zero(int* __restrict__ p, int n) {
  int i = blockIdx.x * 256 + threadIdx.x;
  int s = gridDim.x * 256;
  for (; i < n; i += s) p[i] = 0;
}

__global__ __launch_bounds__(256) void k_hist(const int* __restrict__ src, const int* __restrict__ dst,
                                              int* __restrict__ deg_f, int* __restrict__ deg_m, int E) {
  int i = blockIdx.x * 256 + threadIdx.x;
  int s = gridDim.x * 256;
  for (; i < E; i += s) {
    atomicAdd(&deg_f[src[i]], 1);
    atomicAdd(&deg_m[dst[i]], 1);
  }
}

// chunk = 1024 elements per block (4 per thread); writes chunk-local exclusive scan + block total
__global__ __launch_bounds__(256) void k_scan_chunks(const int* __restrict__ deg, int n,
                                                     int* __restrict__ rowptr, int* __restrict__ part) {
  __shared__ int sm[256];
  int t = threadIdx.x;
  int base = blockIdx.x * 1024 + t * 4;
  int v0 = 0, v1 = 0, v2 = 0, v3 = 0;
  if (base + 0 < n) v0 = deg[base + 0];
  if (base + 1 < n) v1 = deg[base + 1];
  if (base + 2 < n) v2 = deg[base + 2];
  if (base + 3 < n) v3 = deg[base + 3];
  int s = v0 + v1 + v2 + v3;
  sm[t] = s;
  __syncthreads();
  for (int off = 1; off < 256; off <<= 1) {
    int x = (t >= off) ? sm[t - off] : 0;
    __syncthreads();
    sm[t] += x;
    __syncthreads();
  }
  int excl = sm[t] - s;
  if (t == 255) part[blockIdx.x] = sm[255];
  if (base + 0 < n) rowptr[base + 0] = excl;
  if (base + 1 < n) rowptr[base + 1] = excl + v0;
  if (base + 2 < n) rowptr[base + 2] = excl + v0 + v1;
  if (base + 3 < n) rowptr[base + 3] = excl + v0 + v1 + v2;
}

__global__ __launch_bounds__(256) void k_scan_part(int* __restrict__ part, int nb) {
  __shared__ int sm[256];
  int t = threadIdx.x;
  int s = (t < nb) ? part[t] : 0;
  sm[t] = s;
  __syncthreads();
  for (int off = 1; off < 256; off <<= 1) {
    int x = (t >= off) ? sm[t - off] : 0;
    __syncthreads();
    sm[t] += x;
    __syncthreads();
  }
  if (t < nb) part[t] = sm[t] - s;
}

__global__ __launch_bounds__(256) void k_add_off(int* __restrict__ rowptr, const int* __restrict__ part,
                                                 int* __restrict__ cursor, int n, int total) {
  int i = blockIdx.x * 256 + threadIdx.x;
  int s = gridDim.x * 256;
  for (; i < n; i += s) {
    int v = rowptr[i] + part[i >> 10];
    rowptr[i] = v;
    cursor[i] = v;
  }
  if (blockIdx.x == 0 && threadIdx.x == 0) rowptr[n] = total;
}

__global__ __launch_bounds__(256) void k_scatter(const int* __restrict__ src, const int* __restrict__ dst,
                                                 int* __restrict__ cur_f, int* __restrict__ cur_m,
                                                 int* __restrict__ col_f, int* __restrict__ col_m, int E) {
  int i = blockIdx.x * 256 + threadIdx.x;
  int s = gridDim.x * 256;
  for (; i < E; i += s) {
    int a = src[i], b = dst[i];
    int p = atomicAdd(&cur_m[b], 1);
    col_m[p] = a;
    int q = atomicAdd(&cur_f[a], 1);
    col_f[q] = b;
  }
}

// out[r][c] = relu(b[c] + sum_k W[c][k]*x[r][k]); W is [128][din]; din in {5,8}
__global__ __launch_bounds__(256) void k_proj(const float* __restrict__ x, const float* __restrict__ W,
                                              const float* __restrict__ b, u16* __restrict__ out,
                                              int n, int din) {
  __shared__ float Wls[128 * 9];
  __shared__ float bs[128];
  int t = threadIdx.x;
  int sw = din | 1;  // 9 or 5 (odd -> conflict-free-ish)
  for (int i = t; i < 128 * din; i += 256) {
    int c = i / din, k = i - c * din;
    Wls[c * sw + k] = W[i];
  }
  for (int i = t; i < 128; i += 256) bs[i] = b[i];
  __syncthreads();
  int idx = blockIdx.x * 256 + t;
  int gs = gridDim.x * 256;
  for (; idx < n * 64; idx += gs) {
    int row = idx >> 6, cp = (idx & 63) * 2;
    float a0 = bs[cp], a1 = bs[cp + 1];
    const float* xr = x + (size_t)row * din;
    for (int k = 0; k < din; ++k) {
      float xv = xr[k];
      a0 += Wls[cp * sw + k] * xv;
      a1 += Wls[(cp + 1) * sw + k] * xv;
    }
    a0 = fmaxf(a0, 0.f);
    a1 = fmaxf(a1, 0.f);
    u32 pk = (u32)f2bf(a0) | ((u32)f2bf(a1) << 16);
    *(u32*)(out + (size_t)row * HDIM + cp) = pk;
  }
}

// one wave per dst node: out[d][:] = mean over neighbors of feat[idx][:] (bf16 rows)
__global__ __launch_bounds__(256) void k_agg(const u16* __restrict__ feat, const int* __restrict__ rowptr,
                                             const int* __restrict__ col, u16* __restrict__ out, int ndst) {
  int w = (blockIdx.x * 256 + threadIdx.x) >> 6;
  int lane = threadIdx.x & 63;
  if (w >= ndst) return;
  int s0 = rowptr[w], s1 = rowptr[w + 1];
  float a0 = 0.f, a1 = 0.f;
  int j = s0;
  for (; j + 1 < s1; j += 2) {
    int i0 = col[j], i1 = col[j + 1];
    u32 v0 = *(const u32*)(feat + (size_t)i0 * HDIM + lane * 2);
    u32 v1 = *(const u32*)(feat + (size_t)i1 * HDIM + lane * 2);
    a0 += bf2f((u16)v0) + bf2f((u16)v1);
    a1 += bf2f((u16)(v0 >> 16)) + bf2f((u16)(v1 >> 16));
  }
  if (j < s1) {
    u32 v = *(const u32*)(feat + (size_t)col[j] * HDIM + lane * 2);
    a0 += bf2f((u16)v);
    a1 += bf2f((u16)(v >> 16));
  }
  int deg = s1 - s0;
  float inv = deg > 0 ? 1.f / (float)deg : 0.f;
  u32 pk = (u32)f2bf(a0 * inv) | ((u32)f2bf(a1 * inv) << 16);
  *(u32*)(out + (size_t)w * HDIM + lane * 2) = pk;
}

// out = act( bias + X1 @ W1^T [+ X2 @ W2^T] [+ ADD row] ), all K=128, 128 cols, bf16 in/out f32 math
__global__ __launch_bounds__(256) void k_lin(const u16* __restrict__ X1, const float* __restrict__ W1,
                                             const u16* __restrict__ X2, const float* __restrict__ W2,
                                             const u16* __restrict__ ADD, const float* __restrict__ bias,
                                             u16* __restrict__ out, int n, int do_relu) {
  __shared__ float Ws[32][132];
  __shared__ float Xs[32][33];
  int t = threadIdx.x;
  int row0 = blockIdx.x * 32;
  int c4 = (t & 31) * 4;
  int r0 = (t >> 5) * 4;
  float acc[4][4] = {{0.f}};
  const u16* Xp = X1;
  const float* Wp = W1;
  for (int p = 0; p < 2; ++p) {
    for (int k0 = 0; k0 < 128; k0 += 32) {
      int cw = t >> 3;
      int kk = (t & 7) * 4;
      #pragma unroll
      for (int cc = 0; cc < 128; cc += 32) {
        float4 wv = *(const float4*)(Wp + (size_t)(cw + cc) * 128 + k0 + kk);
        Ws[kk + 0][cw + cc] = wv.x;
        Ws[kk + 1][cw + cc] = wv.y;
        Ws[kk + 2][cw + cc] = wv.z;
        Ws[kk + 3][cw + cc] = wv.w;
      }
      {
        int r = t >> 3;
        int row = row0 + r;
        if (row < n) {
          ushort4 xv = *(const ushort4*)(Xp + (size_t)row * 128 + k0 + kk);
          Xs[r][kk + 0] = bf2f(xv.x);
          Xs[r][kk + 1] = bf2f(xv.y);
          Xs[r][kk + 2] = bf2f(xv.z);
          Xs[r][kk + 3] = bf2f(xv.w);
        } else {
          Xs[r][kk + 0] = 0.f; Xs[r][kk + 1] = 0.f; Xs[r][kk + 2] = 0.f; Xs[r][kk + 3] = 0.f;
        }
      }
      __syncthreads();
      #pragma unroll
      for (int k = 0; k < 32; ++k) {
        float4 wv = *(const float4*)&Ws[k][c4];
        #pragma unroll
        for (int j = 0; j < 4; ++j) {
          float xv = Xs[r0 + j][k];
          acc[j][0] += xv * wv.x;
          acc[j][1] += xv * wv.y;
          acc[j][2] += xv * wv.z;
          acc[j][3] += xv * wv.w;
        }
      }
      __syncthreads();
    }
    if (!X2) break;
    Xp = X2;
    Wp = W2;
  }
  float b0 = 0.f, b1 = 0.f, b2 = 0.f, b3 = 0.f;
  if (bias) { b0 = bias[c4]; b1 = bias[c4 + 1]; b2 = bias[c4 + 2]; b3 = bias[c4 + 3]; }
  #pragma unroll
  for (int j = 0; j < 4; ++j) {
    int row = row0 + r0 + j;
    if (row < n) {
      float v0 = acc[j][0] + b0, v1 = acc[j][1] + b1, v2 = acc[j][2] + b2, v3 = acc[j][3] + b3;
      if (ADD) {
        ushort4 av = *(const ushort4*)(ADD + (size_t)row * 128 + c4);
        v0 += bf2f(av.x); v1 += bf2f(av.y); v2 += bf2f(av.z); v3 += bf2f(av.w);
      }
      if (do_relu) {
        v0 = fmaxf(v0, 0.f); v1 = fmaxf(v1, 0.f); v2 = fmaxf(v2, 0.f); v3 = fmaxf(v3, 0.f);
      }
      ushort4 pk;
      pk.x = f2bf(v0); pk.y = f2bf(v1); pk.z = f2bf(v2); pk.w = f2bf(v3);
      *(ushort4*)(out + (size_t)row * 128 + c4) = pk;
    }
  }
}

// fused classifier: out[row] = Wc2 @ relu(Wc1 @ f2row + bc1) + bc2 ; one wave per row
__global__ __launch_bounds__(256) void k_cls(const u16* __restrict__ f2,
                                             const float* __restrict__ Wc1, const float* __restrict__ bc1,
                                             const float* __restrict__ Wc2, const float* __restrict__ bc2,
                                             float* __restrict__ out, int n) {
  __shared__ float W1s[64][129];
  __shared__ float W2s[2][64];
  __shared__ float xsh[4][128];
  int t = threadIdx.x;
  for (int i = t; i < 64 * 128; i += 256) W1s[i >> 7][i & 127] = Wc1[i];
  for (int i = t; i < 128; i += 256) W2s[i >> 6][i & 63] = Wc2[i];
  int wv = t >> 6, lane = t & 63;
  int row = blockIdx.x * 4 + wv;
  bool act = row < n;
  if (act) {
    u32 v = *(const u32*)(f2 + (size_t)row * 128 + lane * 2);
    xsh[wv][lane * 2] = bf2f((u16)v);
    xsh[wv][lane * 2 + 1] = bf2f((u16)(v >> 16));
  }
  __syncthreads();
  if (!act) return;
  float a = 0.f;
  #pragma unroll 4
  for (int k = 0; k < 128; ++k) a += W1s[lane][k] * xsh[wv][k];
  a += bc1[lane];
  a = fmaxf(a, 0.f);
  float p0 = W2s[0][lane] * a;
  float p1 = W2s[1][lane] * a;
  #pragma unroll
  for (int off = 32; off > 0; off >>= 1) {
    p0 += __shfl_down(p0, off);
    p1 += __shfl_down(p1, off);
  }
  if (lane == 0) {
    out[(size_t)row * 2 + 0] = p0 + bc2[0];
    out[(size_t)row * 2 + 1] = p1 + bc2[1];
  }
}

static inline int imin(int a, int b) { return a < b ? a : b; }

extern "C" void kernel_launch(void* const* d_in, const int* in_sizes, int n_in,
                              void* d_out, int out_size, void* d_ws, size_t ws_size,
                              hipStream_t stream) {
  const float* x_fund = (const float*)d_in[0];
  const float* x_mgr  = (const float*)d_in[1];
  const int* fm_src   = (const int*)d_in[2];
  const int* fm_dst   = (const int*)d_in[3];
  const float* Wf = (const float*)d_in[4];
  const float* bfb = (const float*)d_in[5];
  const float* Wm = (const float*)d_in[6];
  const float* bm = (const float*)d_in[7];
  const float* Wl_fm0 = (const float*)d_in[8];
  const float* bl_fm0 = (const float*)d_in[9];
  const float* Wr_fm0 = (const float*)d_in[10];
  const float* Wl_mf0 = (const float*)d_in[11];
  const float* bl_mf0 = (const float*)d_in[12];
  const float* Wr_mf0 = (const float*)d_in[13];
  const float* Wl_mf1 = (const float*)d_in[17];
  const float* bl_mf1 = (const float*)d_in[18];
  const float* Wr_mf1 = (const float*)d_in[19];
  const float* Wc1 = (const float*)d_in[20];
  const float* bc1 = (const float*)d_in[21];
  const float* Wc2 = (const float*)d_in[22];
  const float* bc2 = (const float*)d_in[23];
  // (Wl_fm1/bl_fm1/Wr_fm1 at indices 14..16 are dead: m2 is deleted in the reference)

  int NF = in_sizes[0] / 8;
  int NM = in_sizes[1] / 5;
  int E  = in_sizes[2];

  char* ws = (char*)d_ws;
  size_t off = 0;
  auto alloc = [&](size_t bytes) -> char* {
    char* p = ws + off;
    off += (bytes + 255) & ~(size_t)255;
    return p;
  };
  u16* f_b   = (u16*)alloc((size_t)NF * HDIM * 2);
  u16* f1_b  = (u16*)alloc((size_t)NF * HDIM * 2);
  u16* f2_b  = (u16*)alloc((size_t)NF * HDIM * 2);
  u16* aggf  = (u16*)alloc((size_t)NF * HDIM * 2);
  u16* m_b   = (u16*)alloc((size_t)NM * HDIM * 2);
  u16* m1_b  = (u16*)alloc((size_t)NM * HDIM * 2);
  u16* t_b   = (u16*)alloc((size_t)NM * HDIM * 2);
  u16* aggm  = (u16*)alloc((size_t)NM * HDIM * 2);
  int* rp_f  = (int*)alloc((size_t)(NF + 1) * 4);
  int* rp_m  = (int*)alloc((size_t)(NM + 1) * 4);
  int* cu_f  = (int*)alloc((size_t)NF * 4);
  int* cu_m  = (int*)alloc((size_t)NM * 4);
  int* deg_f = (int*)alloc((size_t)NF * 4);
  int* deg_m = (int*)alloc((size_t)NM * 4);
  int* col_f = (int*)alloc((size_t)E * 4);
  int* col_m = (int*)alloc((size_t)E * 4);
  int* part_f = (int*)alloc(256 * 4);
  int* part_m = (int*)alloc(256 * 4);
  (void)ws_size; (void)n_in; (void)out_size;

  int nbE = imin((E + 255) / 256, 2048);
  int nch_f = (NF + 1023) / 1024;
  int nch_m = (NM + 1023) / 1024;

  // ---- build CSR (both directions) ----
  k_zero<<<imin((NF + 255) / 256, 1024), 256, 0, stream>>>(deg_f, NF);
  k_zero<<<imin((NM + 255) / 256, 1024), 256, 0, stream>>>(deg_m, NM);
  k_hist<<<nbE, 256, 0, stream>>>(fm_src, fm_dst, deg_f, deg_m, E);
  k_scan_chunks<<<nch_f, 256, 0, stream>>>(deg_f, NF, rp_f, part_f);
  k_scan_chunks<<<nch_m, 256, 0, stream>>>(deg_m, NM, rp_m, part_m);
  k_scan_part<<<1, 256, 0, stream>>>(part_f, nch_f);
  k_scan_part<<<1, 256, 0, stream>>>(part_m, nch_m);
  k_add_off<<<(NF + 255) / 256, 256, 0, stream>>>(rp_f, part_f, cu_f, NF, E);
  k_add_off<<<(NM + 255) / 256, 256, 0, stream>>>(rp_m, part_m, cu_m, NM, E);
  k_scatter<<<nbE, 256, 0, stream>>>(fm_src, fm_dst, cu_f, cu_m, col_f, col_m, E);

  // ---- input projections ----
  k_proj<<<imin((NF * 64 + 255) / 256, 4096), 256, 0, stream>>>(x_fund, Wf, bfb, f_b, NF, 8);
  k_proj<<<imin((NM * 64 + 255) / 256, 4096), 256, 0, stream>>>(x_mgr, Wm, bm, m_b, NM, 5);

  // ---- layer 0, fund->manager: m1 = relu(mean_f @ Wl_fm0^T + bl + m @ Wr_fm0^T) ----
  k_agg<<<(NM + 3) / 4, 256, 0, stream>>>(f_b, rp_m, col_m, aggm, NM);
  k_lin<<<(NM + 31) / 32, 256, 0, stream>>>(aggm, Wl_fm0, m_b, Wr_fm0, nullptr, bl_fm0, m1_b, NM, 1);

  // ---- layer 0, manager->fund: f1 = relu(mean(m@Wl_mf0^T) + bl + f @ Wr_mf0^T) ----
  k_lin<<<(NM + 31) / 32, 256, 0, stream>>>(m_b, Wl_mf0, nullptr, nullptr, nullptr, nullptr, t_b, NM, 0);
  k_agg<<<(NF + 3) / 4, 256, 0, stream>>>(t_b, rp_f, col_f, aggf, NF);
  k_lin<<<(NF + 31) / 32, 256, 0, stream>>>(f_b, Wr_mf0, nullptr, nullptr, aggf, bl_mf0, f1_b, NF, 1);

  // ---- layer 1, manager->fund only (m2 is dead): f2 = relu(mean(m1@Wl_mf1^T) + bl + f1 @ Wr_mf1^T) ----
  k_lin<<<(NM + 31) / 32, 256, 0, stream>>>(m1_b, Wl_mf1, nullptr, nullptr, nullptr, nullptr, t_b, NM, 0);
  k_agg<<<(NF + 3) / 4, 256, 0, stream>>>(t_b, rp_f, col_f, aggf, NF);
  k_lin<<<(NF + 31) / 32, 256, 0, stream>>>(f1_b, Wr_mf1, nullptr, nullptr, aggf, bl_mf1, f2_b, NF, 1);

  // ---- classifier on fund nodes ----
  k_cls<<<(NF + 3) / 4, 256, 0, stream>>>(f2_b, Wc1, bc1, Wc2, bc2, (float*)d_out, NF);
}

// Round 2
// 691.704 us; speedup vs baseline: 1.0854x; 1.0854x over previous
//
#include <hip/hip_runtime.h>
#include <hip/hip_bf16.h>

#define HDIM 128

typedef unsigned short u16;
typedef unsigned int u32;

__device__ __forceinline__ float bf2f(u16 u) {
  union { u32 i; float f; } x; x.i = ((u32)u) << 16; return x.f;
}
__device__ __forceinline__ u16 f2bf(float f) {
  union { float f; u32 i; } x; x.f = f;
  u32 r = x.i + 0x7fffu + ((x.i >> 16) & 1u);
  return (u16)(r >> 16);
}

__global__ __launch_bounds__(256) void k_zero(int* __restrict__ p, int n) {
  int i = blockIdx.x * 256 + threadIdx.x;
  int s = gridDim.x * 256;
  for (; i < n; i += s) p[i] = 0;
}

__global__ __launch_bounds__(256) void k_hist(const int* __restrict__ src, const int* __restrict__ dst,
                                              int* __restrict__ deg_f, int* __restrict__ deg_m, int E) {
  int i = blockIdx.x * 256 + threadIdx.x;
  int s = gridDim.x * 256;
  for (; i < E; i += s) {
    int a = __builtin_nontemporal_load(src + i);
    int b = __builtin_nontemporal_load(dst + i);
    atomicAdd(&deg_f[a], 1);
    atomicAdd(&deg_m[b], 1);
  }
}

// chunk = 1024 elements per block (4 per thread); writes chunk-local exclusive scan + block total
__global__ __launch_bounds__(256) void k_scan_chunks(const int* __restrict__ deg, int n,
                                                     int* __restrict__ rowptr, int* __restrict__ part) {
  __shared__ int sm[256];
  int t = threadIdx.x;
  int base = blockIdx.x * 1024 + t * 4;
  int v0 = 0, v1 = 0, v2 = 0, v3 = 0;
  if (base + 0 < n) v0 = deg[base + 0];
  if (base + 1 < n) v1 = deg[base + 1];
  if (base + 2 < n) v2 = deg[base + 2];
  if (base + 3 < n) v3 = deg[base + 3];
  int s = v0 + v1 + v2 + v3;
  sm[t] = s;
  __syncthreads();
  for (int off = 1; off < 256; off <<= 1) {
    int x = (t >= off) ? sm[t - off] : 0;
    __syncthreads();
    sm[t] += x;
    __syncthreads();
  }
  int excl = sm[t] - s;
  if (t == 255) part[blockIdx.x] = sm[255];
  if (base + 0 < n) rowptr[base + 0] = excl;
  if (base + 1 < n) rowptr[base + 1] = excl + v0;
  if (base + 2 < n) rowptr[base + 2] = excl + v0 + v1;
  if (base + 3 < n) rowptr[base + 3] = excl + v0 + v1 + v2;
}

__global__ __launch_bounds__(256) void k_scan_part(int* __restrict__ part, int nb) {
  __shared__ int sm[256];
  int t = threadIdx.x;
  int s = (t < nb) ? part[t] : 0;
  sm[t] = s;
  __syncthreads();
  for (int off = 1; off < 256; off <<= 1) {
    int x = (t >= off) ? sm[t - off] : 0;
    __syncthreads();
    sm[t] += x;
    __syncthreads();
  }
  if (t < nb) part[t] = sm[t] - s;
}

__global__ __launch_bounds__(256) void k_add_off(int* __restrict__ rowptr, const int* __restrict__ part,
                                                 int* __restrict__ cursor, int n, int total) {
  int i = blockIdx.x * 256 + threadIdx.x;
  int s = gridDim.x * 256;
  for (; i < n; i += s) {
    int v = rowptr[i] + part[i >> 10];
    rowptr[i] = v;
    cursor[i] = v;
  }
  if (blockIdx.x == 0 && threadIdx.x == 0) rowptr[n] = total;
}

// dst-range-partitioned scatter: block group g = blockIdx&7 handles keys in
// [nkey*g/8, nkey*(g+1)/8). Random writes confined to ~1/8 of col + cursor,
// which stays L2-resident (kills the 128MB write amplification of a full
// random scatter). Edge stream re-read per group is cheap (streaming, NT).
__global__ __launch_bounds__(256) void k_scatter1(const int* __restrict__ key, const int* __restrict__ val,
                                                  int* __restrict__ cur, int* __restrict__ col,
                                                  int E, int nkey) {
  int g = blockIdx.x & 7;
  int sub = blockIdx.x >> 3;
  int nb = gridDim.x >> 3;
  int lo = (int)(((long long)nkey * g) >> 3);
  int hi = (int)(((long long)nkey * (g + 1)) >> 3);
  int i = sub * 256 + threadIdx.x;
  int s = nb * 256;
  for (; i < E; i += s) {
    int k = __builtin_nontemporal_load(key + i);
    if (k >= lo && k < hi) {
      int v = __builtin_nontemporal_load(val + i);
      int p = atomicAdd(&cur[k], 1);
      col[p] = v;
    }
  }
}

// out[r][c] = relu(b[c] + sum_k W[c][k]*x[r][k]); W is [128][din]; din in {5,8}
__global__ __launch_bounds__(256) void k_proj(const float* __restrict__ x, const float* __restrict__ W,
                                              const float* __restrict__ b, u16* __restrict__ out,
                                              int n, int din) {
  __shared__ float Wls[128 * 9];
  __shared__ float bs[128];
  int t = threadIdx.x;
  int sw = din | 1;  // 9 or 5 (odd -> conflict-free-ish)
  for (int i = t; i < 128 * din; i += 256) {
    int c = i / din, k = i - c * din;
    Wls[c * sw + k] = W[i];
  }
  for (int i = t; i < 128; i += 256) bs[i] = b[i];
  __syncthreads();
  int idx = blockIdx.x * 256 + t;
  int gs = gridDim.x * 256;
  for (; idx < n * 64; idx += gs) {
    int row = idx >> 6, cp = (idx & 63) * 2;
    float a0 = bs[cp], a1 = bs[cp + 1];
    const float* xr = x + (size_t)row * din;
    for (int k = 0; k < din; ++k) {
      float xv = xr[k];
      a0 += Wls[cp * sw + k] * xv;
      a1 += Wls[(cp + 1) * sw + k] * xv;
    }
    a0 = fmaxf(a0, 0.f);
    a1 = fmaxf(a1, 0.f);
    u32 pk = (u32)f2bf(a0) | ((u32)f2bf(a1) << 16);
    *(u32*)(out + (size_t)row * HDIM + cp) = pk;
  }
}

// one wave per dst node: out[d][:] = mean over neighbors of feat[idx][:] (bf16 rows)
__global__ __launch_bounds__(256) void k_agg(const u16* __restrict__ feat, const int* __restrict__ rowptr,
                                             const int* __restrict__ col, u16* __restrict__ out, int ndst) {
  int w = (blockIdx.x * 256 + threadIdx.x) >> 6;
  int lane = threadIdx.x & 63;
  if (w >= ndst) return;
  int s0 = rowptr[w], s1 = rowptr[w + 1];
  float a0 = 0.f, a1 = 0.f, b0 = 0.f, b1 = 0.f;
  int j = s0;
  for (; j + 3 < s1; j += 4) {
    int i0 = col[j], i1 = col[j + 1], i2 = col[j + 2], i3 = col[j + 3];
    u32 v0 = *(const u32*)(feat + (size_t)i0 * HDIM + lane * 2);
    u32 v1 = *(const u32*)(feat + (size_t)i1 * HDIM + lane * 2);
    u32 v2 = *(const u32*)(feat + (size_t)i2 * HDIM + lane * 2);
    u32 v3 = *(const u32*)(feat + (size_t)i3 * HDIM + lane * 2);
    a0 += bf2f((u16)v0) + bf2f((u16)v1);
    a1 += bf2f((u16)(v0 >> 16)) + bf2f((u16)(v1 >> 16));
    b0 += bf2f((u16)v2) + bf2f((u16)v3);
    b1 += bf2f((u16)(v2 >> 16)) + bf2f((u16)(v3 >> 16));
  }
  for (; j < s1; ++j) {
    u32 v = *(const u32*)(feat + (size_t)col[j] * HDIM + lane * 2);
    a0 += bf2f((u16)v);
    a1 += bf2f((u16)(v >> 16));
  }
  a0 += b0;
  a1 += b1;
  int deg = s1 - s0;
  float inv = deg > 0 ? 1.f / (float)deg : 0.f;
  u32 pk = (u32)f2bf(a0 * inv) | ((u32)f2bf(a1 * inv) << 16);
  *(u32*)(out + (size_t)w * HDIM + lane * 2) = pk;
}

// out = act( bias + X1 @ W1^T [+ X2 @ W2^T] [+ ADD row] ), all K=128, 128 cols, bf16 in/out f32 math
__global__ __launch_bounds__(256) void k_lin(const u16* __restrict__ X1, const float* __restrict__ W1,
                                             const u16* __restrict__ X2, const float* __restrict__ W2,
                                             const u16* __restrict__ ADD, const float* __restrict__ bias,
                                             u16* __restrict__ out, int n, int do_relu) {
  __shared__ float Ws[32][132];
  __shared__ float Xs[32][33];
  int t = threadIdx.x;
  int row0 = blockIdx.x * 32;
  int c4 = (t & 31) * 4;
  int r0 = (t >> 5) * 4;
  float acc[4][4] = {{0.f}};
  const u16* Xp = X1;
  const float* Wp = W1;
  for (int p = 0; p < 2; ++p) {
    for (int k0 = 0; k0 < 128; k0 += 32) {
      int cw = t >> 3;
      int kk = (t & 7) * 4;
      #pragma unroll
      for (int cc = 0; cc < 128; cc += 32) {
        float4 wv = *(const float4*)(Wp + (size_t)(cw + cc) * 128 + k0 + kk);
        Ws[kk + 0][cw + cc] = wv.x;
        Ws[kk + 1][cw + cc] = wv.y;
        Ws[kk + 2][cw + cc] = wv.z;
        Ws[kk + 3][cw + cc] = wv.w;
      }
      {
        int r = t >> 3;
        int row = row0 + r;
        if (row < n) {
          ushort4 xv = *(const ushort4*)(Xp + (size_t)row * 128 + k0 + kk);
          Xs[r][kk + 0] = bf2f(xv.x);
          Xs[r][kk + 1] = bf2f(xv.y);
          Xs[r][kk + 2] = bf2f(xv.z);
          Xs[r][kk + 3] = bf2f(xv.w);
        } else {
          Xs[r][kk + 0] = 0.f; Xs[r][kk + 1] = 0.f; Xs[r][kk + 2] = 0.f; Xs[r][kk + 3] = 0.f;
        }
      }
      __syncthreads();
      #pragma unroll
      for (int k = 0; k < 32; ++k) {
        float4 wv = *(const float4*)&Ws[k][c4];
        #pragma unroll
        for (int j = 0; j < 4; ++j) {
          float xv = Xs[r0 + j][k];
          acc[j][0] += xv * wv.x;
          acc[j][1] += xv * wv.y;
          acc[j][2] += xv * wv.z;
          acc[j][3] += xv * wv.w;
        }
      }
      __syncthreads();
    }
    if (!X2) break;
    Xp = X2;
    Wp = W2;
  }
  float b0 = 0.f, b1 = 0.f, b2 = 0.f, b3 = 0.f;
  if (bias) { b0 = bias[c4]; b1 = bias[c4 + 1]; b2 = bias[c4 + 2]; b3 = bias[c4 + 3]; }
  #pragma unroll
  for (int j = 0; j < 4; ++j) {
    int row = row0 + r0 + j;
    if (row < n) {
      float v0 = acc[j][0] + b0, v1 = acc[j][1] + b1, v2 = acc[j][2] + b2, v3 = acc[j][3] + b3;
      if (ADD) {
        ushort4 av = *(const ushort4*)(ADD + (size_t)row * 128 + c4);
        v0 += bf2f(av.x); v1 += bf2f(av.y); v2 += bf2f(av.z); v3 += bf2f(av.w);
      }
      if (do_relu) {
        v0 = fmaxf(v0, 0.f); v1 = fmaxf(v1, 0.f); v2 = fmaxf(v2, 0.f); v3 = fmaxf(v3, 0.f);
      }
      ushort4 pk;
      pk.x = f2bf(v0); pk.y = f2bf(v1); pk.z = f2bf(v2); pk.w = f2bf(v3);
      *(ushort4*)(out + (size_t)row * 128 + c4) = pk;
    }
  }
}

// fused classifier: out[row] = Wc2 @ relu(Wc1 @ f2row + bc1) + bc2 ; one wave per row
__global__ __launch_bounds__(256) void k_cls(const u16* __restrict__ f2,
                                             const float* __restrict__ Wc1, const float* __restrict__ bc1,
                                             const float* __restrict__ Wc2, const float* __restrict__ bc2,
                                             float* __restrict__ out, int n) {
  __shared__ float W1s[64][129];
  __shared__ float W2s[2][64];
  __shared__ float xsh[4][128];
  int t = threadIdx.x;
  for (int i = t; i < 64 * 128; i += 256) W1s[i >> 7][i & 127] = Wc1[i];
  for (int i = t; i < 128; i += 256) W2s[i >> 6][i & 63] = Wc2[i];
  int wv = t >> 6, lane = t & 63;
  int row = blockIdx.x * 4 + wv;
  bool act = row < n;
  if (act) {
    u32 v = *(const u32*)(f2 + (size_t)row * 128 + lane * 2);
    xsh[wv][lane * 2] = bf2f((u16)v);
    xsh[wv][lane * 2 + 1] = bf2f((u16)(v >> 16));
  }
  __syncthreads();
  if (!act) return;
  float a = 0.f;
  #pragma unroll 4
  for (int k = 0; k < 128; ++k) a += W1s[lane][k] * xsh[wv][k];
  a += bc1[lane];
  a = fmaxf(a, 0.f);
  float p0 = W2s[0][lane] * a;
  float p1 = W2s[1][lane] * a;
  #pragma unroll
  for (int off = 32; off > 0; off >>= 1) {
    p0 += __shfl_down(p0, off);
    p1 += __shfl_down(p1, off);
  }
  if (lane == 0) {
    out[(size_t)row * 2 + 0] = p0 + bc2[0];
    out[(size_t)row * 2 + 1] = p1 + bc2[1];
  }
}

static inline int imin(int a, int b) { return a < b ? a : b; }

extern "C" void kernel_launch(void* const* d_in, const int* in_sizes, int n_in,
                              void* d_out, int out_size, void* d_ws, size_t ws_size,
                              hipStream_t stream) {
  const float* x_fund = (const float*)d_in[0];
  const float* x_mgr  = (const float*)d_in[1];
  const int* fm_src   = (const int*)d_in[2];
  const int* fm_dst   = (const int*)d_in[3];
  const float* Wf = (const float*)d_in[4];
  const float* bfb = (const float*)d_in[5];
  const float* Wm = (const float*)d_in[6];
  const float* bm = (const float*)d_in[7];
  const float* Wl_fm0 = (const float*)d_in[8];
  const float* bl_fm0 = (const float*)d_in[9];
  const float* Wr_fm0 = (const float*)d_in[10];
  const float* Wl_mf0 = (const float*)d_in[11];
  const float* bl_mf0 = (const float*)d_in[12];
  const float* Wr_mf0 = (const float*)d_in[13];
  const float* Wl_mf1 = (const float*)d_in[17];
  const float* bl_mf1 = (const float*)d_in[18];
  const float* Wr_mf1 = (const float*)d_in[19];
  const float* Wc1 = (const float*)d_in[20];
  const float* bc1 = (const float*)d_in[21];
  const float* Wc2 = (const float*)d_in[22];
  const float* bc2 = (const float*)d_in[23];
  // (Wl_fm1/bl_fm1/Wr_fm1 at indices 14..16 are dead: m2 is deleted in the reference)

  int NF = in_sizes[0] / 8;
  int NM = in_sizes[1] / 5;
  int E  = in_sizes[2];

  char* ws = (char*)d_ws;
  size_t off = 0;
  auto alloc = [&](size_t bytes) -> char* {
    char* p = ws + off;
    off += (bytes + 255) & ~(size_t)255;
    return p;
  };
  u16* f_b   = (u16*)alloc((size_t)NF * HDIM * 2);
  u16* f1_b  = (u16*)alloc((size_t)NF * HDIM * 2);
  u16* f2_b  = (u16*)alloc((size_t)NF * HDIM * 2);
  u16* aggf  = (u16*)alloc((size_t)NF * HDIM * 2);
  u16* m_b   = (u16*)alloc((size_t)NM * HDIM * 2);
  u16* m1_b  = (u16*)alloc((size_t)NM * HDIM * 2);
  u16* t_b   = (u16*)alloc((size_t)NM * HDIM * 2);
  u16* aggm  = (u16*)alloc((size_t)NM * HDIM * 2);
  int* rp_f  = (int*)alloc((size_t)(NF + 1) * 4);
  int* rp_m  = (int*)alloc((size_t)(NM + 1) * 4);
  int* cu_f  = (int*)alloc((size_t)NF * 4);
  int* cu_m  = (int*)alloc((size_t)NM * 4);
  int* deg_f = (int*)alloc((size_t)NF * 4);
  int* deg_m = (int*)alloc((size_t)NM * 4);
  int* col_f = (int*)alloc((size_t)E * 4);
  int* col_m = (int*)alloc((size_t)E * 4);
  int* part_f = (int*)alloc(256 * 4);
  int* part_m = (int*)alloc(256 * 4);
  (void)ws_size; (void)n_in; (void)out_size;

  int nbE = imin((E + 255) / 256, 2048);
  int nch_f = (NF + 1023) / 1024;
  int nch_m = (NM + 1023) / 1024;

  // ---- build CSR (both directions) ----
  k_zero<<<imin((NF + 255) / 256, 1024), 256, 0, stream>>>(deg_f, NF);
  k_zero<<<imin((NM + 255) / 256, 1024), 256, 0, stream>>>(deg_m, NM);
  k_hist<<<nbE, 256, 0, stream>>>(fm_src, fm_dst, deg_f, deg_m, E);
  k_scan_chunks<<<nch_f, 256, 0, stream>>>(deg_f, NF, rp_f, part_f);
  k_scan_chunks<<<nch_m, 256, 0, stream>>>(deg_m, NM, rp_m, part_m);
  k_scan_part<<<1, 256, 0, stream>>>(part_f, nch_f);
  k_scan_part<<<1, 256, 0, stream>>>(part_m, nch_m);
  k_add_off<<<(NF + 255) / 256, 256, 0, stream>>>(rp_f, part_f, cu_f, NF, E);
  k_add_off<<<(NM + 255) / 256, 256, 0, stream>>>(rp_m, part_m, cu_m, NM, E);
  // dst-range-partitioned scatters (random-write set per block-group ~L2-resident)
  k_scatter1<<<512, 256, 0, stream>>>(fm_dst, fm_src, cu_m, col_m, E, NM);
  k_scatter1<<<512, 256, 0, stream>>>(fm_src, fm_dst, cu_f, col_f, E, NF);

  // ---- input projections ----
  k_proj<<<imin((NF * 64 + 255) / 256, 4096), 256, 0, stream>>>(x_fund, Wf, bfb, f_b, NF, 8);
  k_proj<<<imin((NM * 64 + 255) / 256, 4096), 256, 0, stream>>>(x_mgr, Wm, bm, m_b, NM, 5);

  // ---- layer 0, fund->manager: m1 = relu(mean_f @ Wl_fm0^T + bl + m @ Wr_fm0^T) ----
  k_agg<<<(NM + 3) / 4, 256, 0, stream>>>(f_b, rp_m, col_m, aggm, NM);
  k_lin<<<(NM + 31) / 32, 256, 0, stream>>>(aggm, Wl_fm0, m_b, Wr_fm0, nullptr, bl_fm0, m1_b, NM, 1);

  // ---- layer 0, manager->fund: f1 = relu(mean(m@Wl_mf0^T) + bl + f @ Wr_mf0^T) ----
  k_lin<<<(NM + 31) / 32, 256, 0, stream>>>(m_b, Wl_mf0, nullptr, nullptr, nullptr, nullptr, t_b, NM, 0);
  k_agg<<<(NF + 3) / 4, 256, 0, stream>>>(t_b, rp_f, col_f, aggf, NF);
  k_lin<<<(NF + 31) / 32, 256, 0, stream>>>(f_b, Wr_mf0, nullptr, nullptr, aggf, bl_mf0, f1_b, NF, 1);

  // ---- layer 1, manager->fund only (m2 is dead): f2 = relu(mean(m1@Wl_mf1^T) + bl + f1 @ Wr_mf1^T) ----
  k_lin<<<(NM + 31) / 32, 256, 0, stream>>>(m1_b, Wl_mf1, nullptr, nullptr, nullptr, nullptr, t_b, NM, 0);
  k_agg<<<(NF + 3) / 4, 256, 0, stream>>>(t_b, rp_f, col_f, aggf, NF);
  k_lin<<<(NF + 31) / 32, 256, 0, stream>>>(f1_b, Wr_mf1, nullptr, nullptr, aggf, bl_mf1, f2_b, NF, 1);

  // ---- classifier on fund nodes ----
  k_cls<<<(NF + 3) / 4, 256, 0, stream>>>(f2_b, Wc1, bc1, Wc2, bc2, (float*)d_out, NF);
}

// Round 3
// 608.377 us; speedup vs baseline: 1.2340x; 1.1370x over previous
//
#include <hip/hip_runtime.h>
#include <hip/hip_bf16.h>

#define HDIM 128

typedef unsigned short u16;
typedef unsigned int u32;
typedef __attribute__((ext_vector_type(8))) short bf16x8;
typedef __attribute__((ext_vector_type(4))) float f32x4;

__device__ __forceinline__ float bf2f(u16 u) {
  union { u32 i; float f; } x; x.i = ((u32)u) << 16; return x.f;
}
__device__ __forceinline__ u16 f2bf(float f) {
  union { float f; u32 i; } x; x.f = f;
  u32 r = x.i + 0x7fffu + ((x.i >> 16) & 1u);
  return (u16)(r >> 16);
}

__global__ __launch_bounds__(256) void k_zero(int* __restrict__ p, int n) {
  int i = blockIdx.x * 256 + threadIdx.x;
  int s = gridDim.x * 256;
  for (; i < n; i += s) p[i] = 0;
}

__global__ __launch_bounds__(256) void k_hist(const int* __restrict__ src, const int* __restrict__ dst,
                                              int* __restrict__ deg_f, int* __restrict__ deg_m, int E) {
  int i = blockIdx.x * 256 + threadIdx.x;
  int s = gridDim.x * 256;
  for (; i < E; i += s) {
    int a = __builtin_nontemporal_load(src + i);
    int b = __builtin_nontemporal_load(dst + i);
    atomicAdd(&deg_f[a], 1);
    atomicAdd(&deg_m[b], 1);
  }
}

__global__ __launch_bounds__(256) void k_scan_chunks(const int* __restrict__ deg, int n,
                                                     int* __restrict__ rowptr, int* __restrict__ part) {
  __shared__ int sm[256];
  int t = threadIdx.x;
  int base = blockIdx.x * 1024 + t * 4;
  int v0 = 0, v1 = 0, v2 = 0, v3 = 0;
  if (base + 0 < n) v0 = deg[base + 0];
  if (base + 1 < n) v1 = deg[base + 1];
  if (base + 2 < n) v2 = deg[base + 2];
  if (base + 3 < n) v3 = deg[base + 3];
  int s = v0 + v1 + v2 + v3;
  sm[t] = s;
  __syncthreads();
  for (int off = 1; off < 256; off <<= 1) {
    int x = (t >= off) ? sm[t - off] : 0;
    __syncthreads();
    sm[t] += x;
    __syncthreads();
  }
  int excl = sm[t] - s;
  if (t == 255) part[blockIdx.x] = sm[255];
  if (base + 0 < n) rowptr[base + 0] = excl;
  if (base + 1 < n) rowptr[base + 1] = excl + v0;
  if (base + 2 < n) rowptr[base + 2] = excl + v0 + v1;
  if (base + 3 < n) rowptr[base + 3] = excl + v0 + v1 + v2;
}

__global__ __launch_bounds__(256) void k_scan_part(int* __restrict__ part, int nb) {
  __shared__ int sm[256];
  int t = threadIdx.x;
  int s = (t < nb) ? part[t] : 0;
  sm[t] = s;
  __syncthreads();
  for (int off = 1; off < 256; off <<= 1) {
    int x = (t >= off) ? sm[t - off] : 0;
    __syncthreads();
    sm[t] += x;
    __syncthreads();
  }
  if (t < nb) part[t] = sm[t] - s;
}

__global__ __launch_bounds__(256) void k_add_off(int* __restrict__ rowptr, const int* __restrict__ part,
                                                 int* __restrict__ cursor, int n, int total) {
  int i = blockIdx.x * 256 + threadIdx.x;
  int s = gridDim.x * 256;
  for (; i < n; i += s) {
    int v = rowptr[i] + part[i >> 10];
    rowptr[i] = v;
    cursor[i] = v;
  }
  if (blockIdx.x == 0 && threadIdx.x == 0) rowptr[n] = total;
}

// dst-range-partitioned scatter: block group g = blockIdx&7 handles keys in
// [nkey*g/8, nkey*(g+1)/8) -> random-write set stays ~L2-resident.
__global__ __launch_bounds__(256) void k_scatter1(const int* __restrict__ key, const int* __restrict__ val,
                                                  int* __restrict__ cur, int* __restrict__ col,
                                                  int E, int nkey) {
  int g = blockIdx.x & 7;
  int sub = blockIdx.x >> 3;
  int nb = gridDim.x >> 3;
  int lo = (int)(((long long)nkey * g) >> 3);
  int hi = (int)(((long long)nkey * (g + 1)) >> 3);
  int i = sub * 256 + threadIdx.x;
  int s = nb * 256;
  for (; i < E; i += s) {
    int k = __builtin_nontemporal_load(key + i);
    if (k >= lo && k < hi) {
      int v = __builtin_nontemporal_load(val + i);
      int p = atomicAdd(&cur[k], 1);
      col[p] = v;
    }
  }
}

// convert the 7 weight matrices we need to bf16, packed into one dst buffer
// layout: Wl_fm0@0  Wr_fm0@16384  Wl_mf0@32768  Wr_mf0@49152
//         Wl_mf1@65536  Wr_mf1@81920  Wc1@98304   (total 106496 elems)
__global__ __launch_bounds__(256) void k_w2bf(const float* __restrict__ s0, const float* __restrict__ s1,
                                              const float* __restrict__ s2, const float* __restrict__ s3,
                                              const float* __restrict__ s4, const float* __restrict__ s5,
                                              const float* __restrict__ s6, u16* __restrict__ dst) {
  int i = blockIdx.x * 256 + threadIdx.x;  // grid = 416 blocks exactly
  const float* s; int off = i;
  if (i < 16384) { s = s0; }
  else if (i < 32768) { s = s1; off = i - 16384; }
  else if (i < 49152) { s = s2; off = i - 32768; }
  else if (i < 65536) { s = s3; off = i - 49152; }
  else if (i < 81920) { s = s4; off = i - 65536; }
  else if (i < 98304) { s = s5; off = i - 81920; }
  else { s = s6; off = i - 98304; }
  dst[i] = f2bf(s[off]);
}

// out[r][c] = relu(b[c] + sum_k W[c][k]*x[r][k]); W is [128][din]; din in {5,8}
__global__ __launch_bounds__(256) void k_proj(const float* __restrict__ x, const float* __restrict__ W,
                                              const float* __restrict__ b, u16* __restrict__ out,
                                              int n, int din) {
  __shared__ float Wls[128 * 9];
  __shared__ float bs[128];
  int t = threadIdx.x;
  int sw = din | 1;
  for (int i = t; i < 128 * din; i += 256) {
    int c = i / din, k = i - c * din;
    Wls[c * sw + k] = W[i];
  }
  for (int i = t; i < 128; i += 256) bs[i] = b[i];
  __syncthreads();
  int idx = blockIdx.x * 256 + t;
  int gs = gridDim.x * 256;
  for (; idx < n * 64; idx += gs) {
    int row = idx >> 6, cp = (idx & 63) * 2;
    float a0 = bs[cp], a1 = bs[cp + 1];
    const float* xr = x + (size_t)row * din;
    for (int k = 0; k < din; ++k) {
      float xv = xr[k];
      a0 += Wls[cp * sw + k] * xv;
      a1 += Wls[(cp + 1) * sw + k] * xv;
    }
    a0 = fmaxf(a0, 0.f);
    a1 = fmaxf(a1, 0.f);
    u32 pk = (u32)f2bf(a0) | ((u32)f2bf(a1) << 16);
    *(u32*)(out + (size_t)row * HDIM + cp) = pk;
  }
}

// one wave per dst node: out[d][:] = mean over neighbors of feat[idx][:] (bf16 rows)
__global__ __launch_bounds__(256) void k_agg(const u16* __restrict__ feat, const int* __restrict__ rowptr,
                                             const int* __restrict__ col, u16* __restrict__ out, int ndst) {
  int w = (blockIdx.x * 256 + threadIdx.x) >> 6;
  int lane = threadIdx.x & 63;
  if (w >= ndst) return;
  int s0 = rowptr[w], s1 = rowptr[w + 1];
  float a0 = 0.f, a1 = 0.f, b0 = 0.f, b1 = 0.f;
  int j = s0;
  for (; j + 3 < s1; j += 4) {
    int i0 = col[j], i1 = col[j + 1], i2 = col[j + 2], i3 = col[j + 3];
    u32 v0 = *(const u32*)(feat + (size_t)i0 * HDIM + lane * 2);
    u32 v1 = *(const u32*)(feat + (size_t)i1 * HDIM + lane * 2);
    u32 v2 = *(const u32*)(feat + (size_t)i2 * HDIM + lane * 2);
    u32 v3 = *(const u32*)(feat + (size_t)i3 * HDIM + lane * 2);
    a0 += bf2f((u16)v0) + bf2f((u16)v1);
    a1 += bf2f((u16)(v0 >> 16)) + bf2f((u16)(v1 >> 16));
    b0 += bf2f((u16)v2) + bf2f((u16)v3);
    b1 += bf2f((u16)(v2 >> 16)) + bf2f((u16)(v3 >> 16));
  }
  for (; j < s1; ++j) {
    u32 v = *(const u32*)(feat + (size_t)col[j] * HDIM + lane * 2);
    a0 += bf2f((u16)v);
    a1 += bf2f((u16)(v >> 16));
  }
  a0 += b0;
  a1 += b1;
  int deg = s1 - s0;
  float inv = deg > 0 ? 1.f / (float)deg : 0.f;
  u32 pk = (u32)f2bf(a0 * inv) | ((u32)f2bf(a1 * inv) << 16);
  *(u32*)(out + (size_t)w * HDIM + lane * 2) = pk;
}

// MFMA GEMM: out[n,128](bf16) = act(bias + X1@W1^T [+ X2@W2^T] [+ ADD]); X,W bf16.
// Per wave: 16-row x 128-col tile. A/B frags are single 16B global loads
// (A: row=lane%16, k=8*(lane/16)+j ; B via W row-major since B[k][n]=W[n][k]).
// D: col=lane&15, row=(lane>>4)*4+r (m89-verified).
__global__ __launch_bounds__(256) void k_ling(const u16* __restrict__ X1, const u16* __restrict__ W1,
                                              const u16* __restrict__ X2, const u16* __restrict__ W2,
                                              const u16* __restrict__ ADD, const float* __restrict__ bias,
                                              u16* __restrict__ out, int n, int do_relu) {
  int t = threadIdx.x;
  int w = t >> 6, lane = t & 63;
  int lm = lane & 15, lk = (lane >> 4) * 8;
  int row0 = blockIdx.x * 64 + w * 16;
  if (row0 >= n) return;
  int rA = row0 + lm;
  if (rA >= n) rA = n - 1;
  f32x4 acc[8];
  #pragma unroll
  for (int i = 0; i < 8; ++i) acc[i] = (f32x4){0.f, 0.f, 0.f, 0.f};
  const u16* Xp = X1;
  const u16* Wp = W1;
  for (int p = 0; p < 2; ++p) {
    #pragma unroll
    for (int ks = 0; ks < 4; ++ks) {
      bf16x8 a = *(const bf16x8*)(Xp + (size_t)rA * 128 + ks * 32 + lk);
      #pragma unroll
      for (int nt = 0; nt < 8; ++nt) {
        bf16x8 b = *(const bf16x8*)(Wp + (size_t)(nt * 16 + lm) * 128 + ks * 32 + lk);
        acc[nt] = __builtin_amdgcn_mfma_f32_16x16x32_bf16(a, b, acc[nt], 0, 0, 0);
      }
    }
    if (!X2) break;
    Xp = X2;
    Wp = W2;
  }
  int mBase = row0 + (lane >> 4) * 4;
  #pragma unroll
  for (int nt = 0; nt < 8; ++nt) {
    int c = nt * 16 + lm;
    float bv = bias ? bias[c] : 0.f;
    #pragma unroll
    for (int r = 0; r < 4; ++r) {
      int m = mBase + r;
      if (m < n) {
        float v = acc[nt][r] + bv;
        if (ADD) v += bf2f(ADD[(size_t)m * 128 + c]);
        if (do_relu) v = fmaxf(v, 0.f);
        out[(size_t)m * 128 + c] = f2bf(v);
      }
    }
  }
}

// fused classifier: h = relu(f2@Wc1^T + bc1) via MFMA, then out = h@Wc2^T + bc2
// per-wave LDS for h (no barriers: within-wave RAW is lgkmcnt-ordered).
__global__ __launch_bounds__(256) void k_cls(const u16* __restrict__ f2, const u16* __restrict__ Wc1bf,
                                             const float* __restrict__ bc1, const float* __restrict__ Wc2,
                                             const float* __restrict__ bc2, float* __restrict__ out, int n) {
  __shared__ float hsh[4][16][65];
  int t = threadIdx.x;
  int w = t >> 6, lane = t & 63;
  int lm = lane & 15, lk = (lane >> 4) * 8;
  int row0 = blockIdx.x * 64 + w * 16;
  if (row0 >= n) return;
  int rA = row0 + lm;
  if (rA >= n) rA = n - 1;
  f32x4 acc[4];
  #pragma unroll
  for (int i = 0; i < 4; ++i) acc[i] = (f32x4){0.f, 0.f, 0.f, 0.f};
  #pragma unroll
  for (int ks = 0; ks < 4; ++ks) {
    bf16x8 a = *(const bf16x8*)(f2 + (size_t)rA * 128 + ks * 32 + lk);
    #pragma unroll
    for (int nt = 0; nt < 4; ++nt) {
      bf16x8 b = *(const bf16x8*)(Wc1bf + (size_t)(nt * 16 + lm) * 128 + ks * 32 + lk);
      acc[nt] = __builtin_amdgcn_mfma_f32_16x16x32_bf16(a, b, acc[nt], 0, 0, 0);
    }
  }
  int mrow = (lane >> 4) * 4;
  #pragma unroll
  for (int nt = 0; nt < 4; ++nt) {
    int c = nt * 16 + lm;
    float bv = bc1[c];
    #pragma unroll
    for (int r = 0; r < 4; ++r) hsh[w][mrow + r][c] = fmaxf(acc[nt][r] + bv, 0.f);
  }
  if (lane < 32) {
    int rr = lane >> 1, c = lane & 1;
    int m = row0 + rr;
    if (m < n) {
      float s = 0.f;
      #pragma unroll 8
      for (int k = 0; k < 64; ++k) s += hsh[w][rr][k] * Wc2[c * 64 + k];
      out[(size_t)m * 2 + c] = s + bc2[c];
    }
  }
}

static inline int imin(int a, int b) { return a < b ? a : b; }

extern "C" void kernel_launch(void* const* d_in, const int* in_sizes, int n_in,
                              void* d_out, int out_size, void* d_ws, size_t ws_size,
                              hipStream_t stream) {
  const float* x_fund = (const float*)d_in[0];
  const float* x_mgr  = (const float*)d_in[1];
  const int* fm_src   = (const int*)d_in[2];
  const int* fm_dst   = (const int*)d_in[3];
  const float* Wf = (const float*)d_in[4];
  const float* bfb = (const float*)d_in[5];
  const float* Wm = (const float*)d_in[6];
  const float* bm = (const float*)d_in[7];
  const float* Wl_fm0 = (const float*)d_in[8];
  const float* bl_fm0 = (const float*)d_in[9];
  const float* Wr_fm0 = (const float*)d_in[10];
  const float* Wl_mf0 = (const float*)d_in[11];
  const float* bl_mf0 = (const float*)d_in[12];
  const float* Wr_mf0 = (const float*)d_in[13];
  const float* Wl_mf1 = (const float*)d_in[17];
  const float* bl_mf1 = (const float*)d_in[18];
  const float* Wr_mf1 = (const float*)d_in[19];
  const float* Wc1 = (const float*)d_in[20];
  const float* bc1 = (const float*)d_in[21];
  const float* Wc2 = (const float*)d_in[22];
  const float* bc2 = (const float*)d_in[23];
  // (Wl_fm1/bl_fm1/Wr_fm1 at indices 14..16 are dead: m2 is deleted in the reference)

  int NF = in_sizes[0] / 8;
  int NM = in_sizes[1] / 5;
  int E  = in_sizes[2];

  char* ws = (char*)d_ws;
  size_t off = 0;
  auto alloc = [&](size_t bytes) -> char* {
    char* p = ws + off;
    off += (bytes + 255) & ~(size_t)255;
    return p;
  };
  u16* f_b   = (u16*)alloc((size_t)NF * HDIM * 2);
  u16* f1_b  = (u16*)alloc((size_t)NF * HDIM * 2);
  u16* f2_b  = (u16*)alloc((size_t)NF * HDIM * 2);
  u16* aggf  = (u16*)alloc((size_t)NF * HDIM * 2);
  u16* m_b   = (u16*)alloc((size_t)NM * HDIM * 2);
  u16* m1_b  = (u16*)alloc((size_t)NM * HDIM * 2);
  u16* t_b   = (u16*)alloc((size_t)NM * HDIM * 2);
  u16* aggm  = (u16*)alloc((size_t)NM * HDIM * 2);
  u16* wbf   = (u16*)alloc((size_t)106496 * 2);
  int* rp_f  = (int*)alloc((size_t)(NF + 1) * 4);
  int* rp_m  = (int*)alloc((size_t)(NM + 1) * 4);
  int* cu_f  = (int*)alloc((size_t)NF * 4);
  int* cu_m  = (int*)alloc((size_t)NM * 4);
  int* deg_f = (int*)alloc((size_t)NF * 4);
  int* deg_m = (int*)alloc((size_t)NM * 4);
  int* col_f = (int*)alloc((size_t)E * 4);
  int* col_m = (int*)alloc((size_t)E * 4);
  int* part_f = (int*)alloc(256 * 4);
  int* part_m = (int*)alloc(256 * 4);
  (void)ws_size; (void)n_in; (void)out_size;

  u16* Wlfm0b = wbf + 0;
  u16* Wrfm0b = wbf + 16384;
  u16* Wlmf0b = wbf + 32768;
  u16* Wrmf0b = wbf + 49152;
  u16* Wlmf1b = wbf + 65536;
  u16* Wrmf1b = wbf + 81920;
  u16* Wc1b   = wbf + 98304;

  int nbE = imin((E + 255) / 256, 2048);
  int nch_f = (NF + 1023) / 1024;
  int nch_m = (NM + 1023) / 1024;

  // ---- weight conversion (bf16) ----
  k_w2bf<<<416, 256, 0, stream>>>(Wl_fm0, Wr_fm0, Wl_mf0, Wr_mf0, Wl_mf1, Wr_mf1, Wc1, wbf);

  // ---- build CSR (both directions) ----
  k_zero<<<imin((NF + 255) / 256, 1024), 256, 0, stream>>>(deg_f, NF);
  k_zero<<<imin((NM + 255) / 256, 1024), 256, 0, stream>>>(deg_m, NM);
  k_hist<<<nbE, 256, 0, stream>>>(fm_src, fm_dst, deg_f, deg_m, E);
  k_scan_chunks<<<nch_f, 256, 0, stream>>>(deg_f, NF, rp_f, part_f);
  k_scan_chunks<<<nch_m, 256, 0, stream>>>(deg_m, NM, rp_m, part_m);
  k_scan_part<<<1, 256, 0, stream>>>(part_f, nch_f);
  k_scan_part<<<1, 256, 0, stream>>>(part_m, nch_m);
  k_add_off<<<(NF + 255) / 256, 256, 0, stream>>>(rp_f, part_f, cu_f, NF, E);
  k_add_off<<<(NM + 255) / 256, 256, 0, stream>>>(rp_m, part_m, cu_m, NM, E);
  k_scatter1<<<512, 256, 0, stream>>>(fm_dst, fm_src, cu_m, col_m, E, NM);
  k_scatter1<<<512, 256, 0, stream>>>(fm_src, fm_dst, cu_f, col_f, E, NF);

  // ---- input projections ----
  k_proj<<<imin((NF * 64 + 255) / 256, 4096), 256, 0, stream>>>(x_fund, Wf, bfb, f_b, NF, 8);
  k_proj<<<imin((NM * 64 + 255) / 256, 4096), 256, 0, stream>>>(x_mgr, Wm, bm, m_b, NM, 5);

  // ---- layer 0, fund->manager: m1 = relu(agg(f)@Wl + m@Wr + bl) ----
  k_agg<<<(NM + 3) / 4, 256, 0, stream>>>(f_b, rp_m, col_m, aggm, NM);
  k_ling<<<(NM + 63) / 64, 256, 0, stream>>>(aggm, Wlfm0b, m_b, Wrfm0b, nullptr, bl_fm0, m1_b, NM, 1);

  // ---- layer 0, manager->fund: f1 = relu(agg(m@Wl) + f@Wr + bl) ----
  k_ling<<<(NM + 63) / 64, 256, 0, stream>>>(m_b, Wlmf0b, nullptr, nullptr, nullptr, nullptr, t_b, NM, 0);
  k_agg<<<(NF + 3) / 4, 256, 0, stream>>>(t_b, rp_f, col_f, aggf, NF);
  k_ling<<<(NF + 63) / 64, 256, 0, stream>>>(f_b, Wrmf0b, nullptr, nullptr, aggf, bl_mf0, f1_b, NF, 1);

  // ---- layer 1, manager->fund only (m2 dead): f2 = relu(agg(m1@Wl) + f1@Wr + bl) ----
  k_ling<<<(NM + 63) / 64, 256, 0, stream>>>(m1_b, Wlmf1b, nullptr, nullptr, nullptr, nullptr, t_b, NM, 0);
  k_agg<<<(NF + 3) / 4, 256, 0, stream>>>(t_b, rp_f, col_f, aggf, NF);
  k_ling<<<(NF + 63) / 64, 256, 0, stream>>>(f1_b, Wrmf1b, nullptr, nullptr, aggf, bl_mf1, f2_b, NF, 1);

  // ---- classifier on fund nodes ----
  k_cls<<<(NF + 63) / 64, 256, 0, stream>>>(f2_b, Wc1b, bc1, Wc2, bc2, (float*)d_out, NF);
}

// Round 4
// 427.433 us; speedup vs baseline: 1.7565x; 1.4233x over previous
//
#include <hip/hip_runtime.h>
#include <hip/hip_bf16.h>

#define HDIM 128
#define NG 8      // key-range groups (per-XCD-ish L2/LDS partitioning)
#define NB 32     // edge chunks

typedef unsigned short u16;
typedef unsigned int u32;
typedef __attribute__((ext_vector_type(8))) short bf16x8;
typedef __attribute__((ext_vector_type(4))) float f32x4;

__device__ __forceinline__ float bf2f(u16 u) {
  union { u32 i; float f; } x; x.i = ((u32)u) << 16; return x.f;
}
__device__ __forceinline__ u16 f2bf(float f) {
  union { float f; u32 i; } x; x.f = f;
  u32 r = x.i + 0x7fffu + ((x.i >> 16) & 1u);
  return (u16)(r >> 16);
}

static __device__ __forceinline__ int dmin(int a, int b) { return a < b ? a : b; }

// ---- atomic-free CSR phase 1: per-(range,chunk) LDS histogram ----
// grid = NG*NB blocks, 1024 threads. cnt layout: [NB][K], K = NF+NM.
__global__ __launch_bounds__(1024) void k_hist2(const int* __restrict__ src, const int* __restrict__ dst,
                                                int* __restrict__ cnt, int E, int NF, int NM) {
  __shared__ int h[15104];  // NFg + NMg = 12500 + 2500 for the nominal sizes
  int g = blockIdx.x & (NG - 1);
  int c = blockIdx.x >> 3;
  int t = threadIdx.x;
  int NFg = (NF + NG - 1) / NG, NMg = (NM + NG - 1) / NG;
  int loF = g * NFg, hiF = dmin(NF, loF + NFg);
  int loM = g * NMg, hiM = dmin(NM, loM + NMg);
  int nb = NFg + NMg;
  for (int j = t; j < nb; j += 1024) h[j] = 0;
  __syncthreads();
  int Epc = (E + NB - 1) / NB;
  int c0 = c * Epc, c1 = dmin(E, c0 + Epc);
  for (int i = c0 + t; i < c1; i += 1024) {
    int s = src[i], d = dst[i];
    if (s >= loF && s < hiF) atomicAdd(&h[s - loF], 1);
    if (d >= loM && d < hiM) atomicAdd(&h[NFg + (d - loM)], 1);
  }
  __syncthreads();
  size_t K = (size_t)NF + NM;
  int* cc = cnt + (size_t)c * K;
  for (int j = t; j < NFg; j += 1024) {
    int k = loF + j;
    if (k < hiF) cc[k] = h[j];
  }
  for (int j = t; j < NMg; j += 1024) {
    int k = loM + j;
    if (k < hiM) cc[NF + k] = h[NFg + j];
  }
}

// ---- phase 2: per-key exclusive scan over chunks (in-place) + degree ----
__global__ __launch_bounds__(256) void k_colscan(int* __restrict__ cnt, int* __restrict__ deg, int K) {
  int k = blockIdx.x * 256 + threadIdx.x;
  if (k >= K) return;
  int s = 0;
  #pragma unroll 4
  for (int c = 0; c < NB; ++c) {
    int* p = cnt + (size_t)c * K + k;
    int v = *p;
    *p = s;
    s += v;
  }
  deg[k] = s;
}

// chunk = 1024 elements per block (4 per thread); chunk-local scan + block total
__global__ __launch_bounds__(256) void k_scan_chunks(const int* __restrict__ deg, int n,
                                                     int* __restrict__ rowptr, int* __restrict__ part) {
  __shared__ int sm[256];
  int t = threadIdx.x;
  int base = blockIdx.x * 1024 + t * 4;
  int v0 = 0, v1 = 0, v2 = 0, v3 = 0;
  if (base + 0 < n) v0 = deg[base + 0];
  if (base + 1 < n) v1 = deg[base + 1];
  if (base + 2 < n) v2 = deg[base + 2];
  if (base + 3 < n) v3 = deg[base + 3];
  int s = v0 + v1 + v2 + v3;
  sm[t] = s;
  __syncthreads();
  for (int off = 1; off < 256; off <<= 1) {
    int x = (t >= off) ? sm[t - off] : 0;
    __syncthreads();
    sm[t] += x;
    __syncthreads();
  }
  int excl = sm[t] - s;
  if (t == 255) part[blockIdx.x] = sm[255];
  if (base + 0 < n) rowptr[base + 0] = excl;
  if (base + 1 < n) rowptr[base + 1] = excl + v0;
  if (base + 2 < n) rowptr[base + 2] = excl + v0 + v1;
  if (base + 3 < n) rowptr[base + 3] = excl + v0 + v1 + v2;
}

__global__ __launch_bounds__(256) void k_scan_part(int* __restrict__ part, int nb) {
  __shared__ int sm[256];
  int t = threadIdx.x;
  int s = (t < nb) ? part[t] : 0;
  sm[t] = s;
  __syncthreads();
  for (int off = 1; off < 256; off <<= 1) {
    int x = (t >= off) ? sm[t - off] : 0;
    __syncthreads();
    sm[t] += x;
    __syncthreads();
  }
  if (t < nb) part[t] = sm[t] - s;
}

__global__ __launch_bounds__(256) void k_add_off(int* __restrict__ rowptr, const int* __restrict__ part,
                                                 int n, int total) {
  int i = blockIdx.x * 256 + threadIdx.x;
  int s = gridDim.x * 256;
  for (; i < n; i += s) rowptr[i] += part[i >> 10];
  if (blockIdx.x == 0 && threadIdx.x == 0) rowptr[n] = total;
}

// ---- phase 3: atomic-free scatter via LDS cursors (slots pre-reserved) ----
__global__ __launch_bounds__(1024) void k_scatter2(const int* __restrict__ src, const int* __restrict__ dst,
                                                   const int* __restrict__ rp_f, const int* __restrict__ rp_m,
                                                   const int* __restrict__ cnt,
                                                   int* __restrict__ col_f, int* __restrict__ col_m,
                                                   int E, int NF, int NM) {
  __shared__ int cur[15104];
  int g = blockIdx.x & (NG - 1);
  int c = blockIdx.x >> 3;
  int t = threadIdx.x;
  int NFg = (NF + NG - 1) / NG, NMg = (NM + NG - 1) / NG;
  int loF = g * NFg, hiF = dmin(NF, loF + NFg);
  int loM = g * NMg, hiM = dmin(NM, loM + NMg);
  size_t K = (size_t)NF + NM;
  const int* cc = cnt + (size_t)c * K;
  for (int j = t; j < NFg; j += 1024) {
    int k = loF + j;
    if (k < hiF) cur[j] = rp_f[k] + cc[k];
  }
  for (int j = t; j < NMg; j += 1024) {
    int k = loM + j;
    if (k < hiM) cur[NFg + j] = rp_m[k] + cc[NF + k];
  }
  __syncthreads();
  int Epc = (E + NB - 1) / NB;
  int c0 = c * Epc, c1 = dmin(E, c0 + Epc);
  for (int i = c0 + t; i < c1; i += 1024) {
    int s = src[i], d = dst[i];
    if (s >= loF && s < hiF) {
      int p = atomicAdd(&cur[s - loF], 1);  // LDS atomic (CU-local, cheap)
      col_f[p] = d;
    }
    if (d >= loM && d < hiM) {
      int p = atomicAdd(&cur[NFg + (d - loM)], 1);
      col_m[p] = s;
    }
  }
}

// convert the 7 weight matrices we need to bf16, packed into one dst buffer
__global__ __launch_bounds__(256) void k_w2bf(const float* __restrict__ s0, const float* __restrict__ s1,
                                              const float* __restrict__ s2, const float* __restrict__ s3,
                                              const float* __restrict__ s4, const float* __restrict__ s5,
                                              const float* __restrict__ s6, u16* __restrict__ dst) {
  int i = blockIdx.x * 256 + threadIdx.x;  // grid = 416 blocks exactly
  const float* s; int off = i;
  if (i < 16384) { s = s0; }
  else if (i < 32768) { s = s1; off = i - 16384; }
  else if (i < 49152) { s = s2; off = i - 32768; }
  else if (i < 65536) { s = s3; off = i - 49152; }
  else if (i < 81920) { s = s4; off = i - 65536; }
  else if (i < 98304) { s = s5; off = i - 81920; }
  else { s = s6; off = i - 98304; }
  dst[i] = f2bf(s[off]);
}

// out[r][c] = relu(b[c] + sum_k W[c][k]*x[r][k]); W is [128][din]; din in {5,8}
__global__ __launch_bounds__(256) void k_proj(const float* __restrict__ x, const float* __restrict__ W,
                                              const float* __restrict__ b, u16* __restrict__ out,
                                              int n, int din) {
  __shared__ float Wls[128 * 9];
  __shared__ float bs[128];
  int t = threadIdx.x;
  int sw = din | 1;
  for (int i = t; i < 128 * din; i += 256) {
    int c = i / din, k = i - c * din;
    Wls[c * sw + k] = W[i];
  }
  for (int i = t; i < 128; i += 256) bs[i] = b[i];
  __syncthreads();
  int idx = blockIdx.x * 256 + t;
  int gs = gridDim.x * 256;
  for (; idx < n * 64; idx += gs) {
    int row = idx >> 6, cp = (idx & 63) * 2;
    float a0 = bs[cp], a1 = bs[cp + 1];
    const float* xr = x + (size_t)row * din;
    for (int k = 0; k < din; ++k) {
      float xv = xr[k];
      a0 += Wls[cp * sw + k] * xv;
      a1 += Wls[(cp + 1) * sw + k] * xv;
    }
    a0 = fmaxf(a0, 0.f);
    a1 = fmaxf(a1, 0.f);
    u32 pk = (u32)f2bf(a0) | ((u32)f2bf(a1) << 16);
    *(u32*)(out + (size_t)row * HDIM + cp) = pk;
  }
}

// one wave per dst node: out[d][:] = mean over neighbors of feat[idx][:] (bf16 rows)
__global__ __launch_bounds__(256) void k_agg(const u16* __restrict__ feat, const int* __restrict__ rowptr,
                                             const int* __restrict__ col, u16* __restrict__ out, int ndst) {
  int w = (blockIdx.x * 256 + threadIdx.x) >> 6;
  int lane = threadIdx.x & 63;
  if (w >= ndst) return;
  int s0 = rowptr[w], s1 = rowptr[w + 1];
  float a0 = 0.f, a1 = 0.f, b0 = 0.f, b1 = 0.f;
  int j = s0;
  for (; j + 3 < s1; j += 4) {
    int i0 = col[j], i1 = col[j + 1], i2 = col[j + 2], i3 = col[j + 3];
    u32 v0 = *(const u32*)(feat + (size_t)i0 * HDIM + lane * 2);
    u32 v1 = *(const u32*)(feat + (size_t)i1 * HDIM + lane * 2);
    u32 v2 = *(const u32*)(feat + (size_t)i2 * HDIM + lane * 2);
    u32 v3 = *(const u32*)(feat + (size_t)i3 * HDIM + lane * 2);
    a0 += bf2f((u16)v0) + bf2f((u16)v1);
    a1 += bf2f((u16)(v0 >> 16)) + bf2f((u16)(v1 >> 16));
    b0 += bf2f((u16)v2) + bf2f((u16)v3);
    b1 += bf2f((u16)(v2 >> 16)) + bf2f((u16)(v3 >> 16));
  }
  for (; j < s1; ++j) {
    u32 v = *(const u32*)(feat + (size_t)col[j] * HDIM + lane * 2);
    a0 += bf2f((u16)v);
    a1 += bf2f((u16)(v >> 16));
  }
  a0 += b0;
  a1 += b1;
  int deg = s1 - s0;
  float inv = deg > 0 ? 1.f / (float)deg : 0.f;
  u32 pk = (u32)f2bf(a0 * inv) | ((u32)f2bf(a1 * inv) << 16);
  *(u32*)(out + (size_t)w * HDIM + lane * 2) = pk;
}

// MFMA GEMM: out[n,128](bf16) = act(bias + X1@W1^T [+ X2@W2^T] [+ ADD]); X,W bf16.
__global__ __launch_bounds__(256) void k_ling(const u16* __restrict__ X1, const u16* __restrict__ W1,
                                              const u16* __restrict__ X2, const u16* __restrict__ W2,
                                              const u16* __restrict__ ADD, const float* __restrict__ bias,
                                              u16* __restrict__ out, int n, int do_relu) {
  int t = threadIdx.x;
  int w = t >> 6, lane = t & 63;
  int lm = lane & 15, lk = (lane >> 4) * 8;
  int row0 = blockIdx.x * 64 + w * 16;
  if (row0 >= n) return;
  int rA = row0 + lm;
  if (rA >= n) rA = n - 1;
  f32x4 acc[8];
  #pragma unroll
  for (int i = 0; i < 8; ++i) acc[i] = (f32x4){0.f, 0.f, 0.f, 0.f};
  const u16* Xp = X1;
  const u16* Wp = W1;
  for (int p = 0; p < 2; ++p) {
    #pragma unroll
    for (int ks = 0; ks < 4; ++ks) {
      bf16x8 a = *(const bf16x8*)(Xp + (size_t)rA * 128 + ks * 32 + lk);
      #pragma unroll
      for (int nt = 0; nt < 8; ++nt) {
        bf16x8 b = *(const bf16x8*)(Wp + (size_t)(nt * 16 + lm) * 128 + ks * 32 + lk);
        acc[nt] = __builtin_amdgcn_mfma_f32_16x16x32_bf16(a, b, acc[nt], 0, 0, 0);
      }
    }
    if (!X2) break;
    Xp = X2;
    Wp = W2;
  }
  int mBase = row0 + (lane >> 4) * 4;
  #pragma unroll
  for (int nt = 0; nt < 8; ++nt) {
    int c = nt * 16 + lm;
    float bv = bias ? bias[c] : 0.f;
    #pragma unroll
    for (int r = 0; r < 4; ++r) {
      int m = mBase + r;
      if (m < n) {
        float v = acc[nt][r] + bv;
        if (ADD) v += bf2f(ADD[(size_t)m * 128 + c]);
        if (do_relu) v = fmaxf(v, 0.f);
        out[(size_t)m * 128 + c] = f2bf(v);
      }
    }
  }
}

// fused classifier: h = relu(f2@Wc1^T + bc1) via MFMA, then out = h@Wc2^T + bc2
__global__ __launch_bounds__(256) void k_cls(const u16* __restrict__ f2, const u16* __restrict__ Wc1bf,
                                             const float* __restrict__ bc1, const float* __restrict__ Wc2,
                                             const float* __restrict__ bc2, float* __restrict__ out, int n) {
  __shared__ float hsh[4][16][65];
  int t = threadIdx.x;
  int w = t >> 6, lane = t & 63;
  int lm = lane & 15, lk = (lane >> 4) * 8;
  int row0 = blockIdx.x * 64 + w * 16;
  if (row0 >= n) return;
  int rA = row0 + lm;
  if (rA >= n) rA = n - 1;
  f32x4 acc[4];
  #pragma unroll
  for (int i = 0; i < 4; ++i) acc[i] = (f32x4){0.f, 0.f, 0.f, 0.f};
  #pragma unroll
  for (int ks = 0; ks < 4; ++ks) {
    bf16x8 a = *(const bf16x8*)(f2 + (size_t)rA * 128 + ks * 32 + lk);
    #pragma unroll
    for (int nt = 0; nt < 4; ++nt) {
      bf16x8 b = *(const bf16x8*)(Wc1bf + (size_t)(nt * 16 + lm) * 128 + ks * 32 + lk);
      acc[nt] = __builtin_amdgcn_mfma_f32_16x16x32_bf16(a, b, acc[nt], 0, 0, 0);
    }
  }
  int mrow = (lane >> 4) * 4;
  #pragma unroll
  for (int nt = 0; nt < 4; ++nt) {
    int c = nt * 16 + lm;
    float bv = bc1[c];
    #pragma unroll
    for (int r = 0; r < 4; ++r) hsh[w][mrow + r][c] = fmaxf(acc[nt][r] + bv, 0.f);
  }
  if (lane < 32) {
    int rr = lane >> 1, c = lane & 1;
    int m = row0 + rr;
    if (m < n) {
      float s = 0.f;
      #pragma unroll 8
      for (int k = 0; k < 64; ++k) s += hsh[w][rr][k] * Wc2[c * 64 + k];
      out[(size_t)m * 2 + c] = s + bc2[c];
    }
  }
}

static inline int imin(int a, int b) { return a < b ? a : b; }

extern "C" void kernel_launch(void* const* d_in, const int* in_sizes, int n_in,
                              void* d_out, int out_size, void* d_ws, size_t ws_size,
                              hipStream_t stream) {
  const float* x_fund = (const float*)d_in[0];
  const float* x_mgr  = (const float*)d_in[1];
  const int* fm_src   = (const int*)d_in[2];
  const int* fm_dst   = (const int*)d_in[3];
  const float* Wf = (const float*)d_in[4];
  const float* bfb = (const float*)d_in[5];
  const float* Wm = (const float*)d_in[6];
  const float* bm = (const float*)d_in[7];
  const float* Wl_fm0 = (const float*)d_in[8];
  const float* bl_fm0 = (const float*)d_in[9];
  const float* Wr_fm0 = (const float*)d_in[10];
  const float* Wl_mf0 = (const float*)d_in[11];
  const float* bl_mf0 = (const float*)d_in[12];
  const float* Wr_mf0 = (const float*)d_in[13];
  const float* Wl_mf1 = (const float*)d_in[17];
  const float* bl_mf1 = (const float*)d_in[18];
  const float* Wr_mf1 = (const float*)d_in[19];
  const float* Wc1 = (const float*)d_in[20];
  const float* bc1 = (const float*)d_in[21];
  const float* Wc2 = (const float*)d_in[22];
  const float* bc2 = (const float*)d_in[23];
  // (Wl_fm1/bl_fm1/Wr_fm1 at indices 14..16 are dead: m2 is deleted in the reference)

  int NF = in_sizes[0] / 8;
  int NM = in_sizes[1] / 5;
  int E  = in_sizes[2];
  int K  = NF + NM;

  char* ws = (char*)d_ws;
  size_t off = 0;
  auto alloc = [&](size_t bytes) -> char* {
    char* p = ws + off;
    off += (bytes + 255) & ~(size_t)255;
    return p;
  };
  u16* f_b   = (u16*)alloc((size_t)NF * HDIM * 2);
  u16* f1_b  = (u16*)alloc((size_t)NF * HDIM * 2);
  u16* f2_b  = (u16*)alloc((size_t)NF * HDIM * 2);
  u16* aggf  = (u16*)alloc((size_t)NF * HDIM * 2);
  u16* m_b   = (u16*)alloc((size_t)NM * HDIM * 2);
  u16* m1_b  = (u16*)alloc((size_t)NM * HDIM * 2);
  u16* t_b   = (u16*)alloc((size_t)NM * HDIM * 2);
  u16* aggm  = (u16*)alloc((size_t)NM * HDIM * 2);
  u16* wbf   = (u16*)alloc((size_t)106496 * 2);
  int* rp_f  = (int*)alloc((size_t)(NF + 1) * 4);
  int* rp_m  = (int*)alloc((size_t)(NM + 1) * 4);
  int* deg   = (int*)alloc((size_t)K * 4);
  int* col_f = (int*)alloc((size_t)E * 4);
  int* col_m = (int*)alloc((size_t)E * 4);
  int* cnt   = (int*)alloc((size_t)NB * K * 4);
  int* part_f = (int*)alloc(256 * 4);
  int* part_m = (int*)alloc(256 * 4);
  (void)ws_size; (void)n_in; (void)out_size;

  u16* Wlfm0b = wbf + 0;
  u16* Wrfm0b = wbf + 16384;
  u16* Wlmf0b = wbf + 32768;
  u16* Wrmf0b = wbf + 49152;
  u16* Wlmf1b = wbf + 65536;
  u16* Wrmf1b = wbf + 81920;
  u16* Wc1b   = wbf + 98304;

  int nch_f = (NF + 1023) / 1024;
  int nch_m = (NM + 1023) / 1024;

  // ---- weight conversion (bf16) ----
  k_w2bf<<<416, 256, 0, stream>>>(Wl_fm0, Wr_fm0, Wl_mf0, Wr_mf0, Wl_mf1, Wr_mf1, Wc1, wbf);

  // ---- atomic-free CSR build ----
  k_hist2<<<NG * NB, 1024, 0, stream>>>(fm_src, fm_dst, cnt, E, NF, NM);
  k_colscan<<<(K + 255) / 256, 256, 0, stream>>>(cnt, deg, K);
  k_scan_chunks<<<nch_f, 256, 0, stream>>>(deg, NF, rp_f, part_f);
  k_scan_chunks<<<nch_m, 256, 0, stream>>>(deg + NF, NM, rp_m, part_m);
  k_scan_part<<<1, 256, 0, stream>>>(part_f, nch_f);
  k_scan_part<<<1, 256, 0, stream>>>(part_m, nch_m);
  k_add_off<<<(NF + 255) / 256, 256, 0, stream>>>(rp_f, part_f, NF, E);
  k_add_off<<<(NM + 255) / 256, 256, 0, stream>>>(rp_m, part_m, NM, E);
  k_scatter2<<<NG * NB, 1024, 0, stream>>>(fm_src, fm_dst, rp_f, rp_m, cnt, col_f, col_m, E, NF, NM);

  // ---- input projections ----
  k_proj<<<imin((NF * 64 + 255) / 256, 4096), 256, 0, stream>>>(x_fund, Wf, bfb, f_b, NF, 8);
  k_proj<<<imin((NM * 64 + 255) / 256, 4096), 256, 0, stream>>>(x_mgr, Wm, bm, m_b, NM, 5);

  // ---- layer 0, fund->manager: m1 = relu(agg(f)@Wl + m@Wr + bl) ----
  k_agg<<<(NM + 3) / 4, 256, 0, stream>>>(f_b, rp_m, col_m, aggm, NM);
  k_ling<<<(NM + 63) / 64, 256, 0, stream>>>(aggm, Wlfm0b, m_b, Wrfm0b, nullptr, bl_fm0, m1_b, NM, 1);

  // ---- layer 0, manager->fund: f1 = relu(agg(m@Wl) + f@Wr + bl) ----
  k_ling<<<(NM + 63) / 64, 256, 0, stream>>>(m_b, Wlmf0b, nullptr, nullptr, nullptr, nullptr, t_b, NM, 0);
  k_agg<<<(NF + 3) / 4, 256, 0, stream>>>(t_b, rp_f, col_f, aggf, NF);
  k_ling<<<(NF + 63) / 64, 256, 0, stream>>>(f_b, Wrmf0b, nullptr, nullptr, aggf, bl_mf0, f1_b, NF, 1);

  // ---- layer 1, manager->fund only (m2 dead): f2 = relu(agg(m1@Wl) + f1@Wr + bl) ----
  k_ling<<<(NM + 63) / 64, 256, 0, stream>>>(m1_b, Wlmf1b, nullptr, nullptr, nullptr, nullptr, t_b, NM, 0);
  k_agg<<<(NF + 3) / 4, 256, 0, stream>>>(t_b, rp_f, col_f, aggf, NF);
  k_ling<<<(NF + 63) / 64, 256, 0, stream>>>(f1_b, Wrmf1b, nullptr, nullptr, aggf, bl_mf1, f2_b, NF, 1);

  // ---- classifier on fund nodes ----
  k_cls<<<(NF + 63) / 64, 256, 0, stream>>>(f2_b, Wc1b, bc1, Wc2, bc2, (float*)d_out, NF);
}

// Round 5
// 366.465 us; speedup vs baseline: 2.0487x; 1.1664x over previous
//
#include <hip/hip_runtime.h>
#include <hip/hip_bf16.h>

#define HDIM 128
#define NG 8      // key-range groups (per-XCD-ish L2/LDS partitioning)
#define NB 32     // edge chunks

typedef unsigned short u16;
typedef unsigned int u32;
typedef __attribute__((ext_vector_type(8))) short bf16x8;
typedef __attribute__((ext_vector_type(4))) float f32x4;

__device__ __forceinline__ float bf2f(u16 u) {
  union { u32 i; float f; } x; x.i = ((u32)u) << 16; return x.f;
}
__device__ __forceinline__ u16 f2bf(float f) {
  union { float f; u32 i; } x; x.f = f;
  u32 r = x.i + 0x7fffu + ((x.i >> 16) & 1u);
  return (u16)(r >> 16);
}

static __device__ __forceinline__ int dmin(int a, int b) { return a < b ? a : b; }

// ---- atomic-free CSR phase 1: per-(range,chunk) LDS histogram ----
__global__ __launch_bounds__(1024) void k_hist2(const int* __restrict__ src, const int* __restrict__ dst,
                                                int* __restrict__ cnt, int E, int NF, int NM) {
  __shared__ int h[15104];
  int g = blockIdx.x & (NG - 1);
  int c = blockIdx.x >> 3;
  int t = threadIdx.x;
  int NFg = (NF + NG - 1) / NG, NMg = (NM + NG - 1) / NG;
  int loF = g * NFg, hiF = dmin(NF, loF + NFg);
  int loM = g * NMg, hiM = dmin(NM, loM + NMg);
  int nb = NFg + NMg;
  for (int j = t; j < nb; j += 1024) h[j] = 0;
  __syncthreads();
  int Epc = (E + NB - 1) / NB;
  int c0 = c * Epc, c1 = dmin(E, c0 + Epc);
  for (int i = c0 + t; i < c1; i += 1024) {
    int s = src[i], d = dst[i];
    if (s >= loF && s < hiF) atomicAdd(&h[s - loF], 1);
    if (d >= loM && d < hiM) atomicAdd(&h[NFg + (d - loM)], 1);
  }
  __syncthreads();
  size_t K = (size_t)NF + NM;
  int* cc = cnt + (size_t)c * K;
  for (int j = t; j < NFg; j += 1024) {
    int k = loF + j;
    if (k < hiF) cc[k] = h[j];
  }
  for (int j = t; j < NMg; j += 1024) {
    int k = loM + j;
    if (k < hiM) cc[NF + k] = h[NFg + j];
  }
}

// ---- phase 2: per-key exclusive scan over chunks (in-place) + degree ----
__global__ __launch_bounds__(256) void k_colscan(int* __restrict__ cnt, int* __restrict__ deg, int K) {
  int k = blockIdx.x * 256 + threadIdx.x;
  if (k >= K) return;
  int s = 0;
  #pragma unroll 4
  for (int c = 0; c < NB; ++c) {
    int* p = cnt + (size_t)c * K + k;
    int v = *p;
    *p = s;
    s += v;
  }
  deg[k] = s;
}

__global__ __launch_bounds__(256) void k_scan_chunks(const int* __restrict__ deg, int n,
                                                     int* __restrict__ rowptr, int* __restrict__ part) {
  __shared__ int sm[256];
  int t = threadIdx.x;
  int base = blockIdx.x * 1024 + t * 4;
  int v0 = 0, v1 = 0, v2 = 0, v3 = 0;
  if (base + 0 < n) v0 = deg[base + 0];
  if (base + 1 < n) v1 = deg[base + 1];
  if (base + 2 < n) v2 = deg[base + 2];
  if (base + 3 < n) v3 = deg[base + 3];
  int s = v0 + v1 + v2 + v3;
  sm[t] = s;
  __syncthreads();
  for (int off = 1; off < 256; off <<= 1) {
    int x = (t >= off) ? sm[t - off] : 0;
    __syncthreads();
    sm[t] += x;
    __syncthreads();
  }
  int excl = sm[t] - s;
  if (t == 255) part[blockIdx.x] = sm[255];
  if (base + 0 < n) rowptr[base + 0] = excl;
  if (base + 1 < n) rowptr[base + 1] = excl + v0;
  if (base + 2 < n) rowptr[base + 2] = excl + v0 + v1;
  if (base + 3 < n) rowptr[base + 3] = excl + v0 + v1 + v2;
}

__global__ __launch_bounds__(256) void k_scan_part(int* __restrict__ part, int nb) {
  __shared__ int sm[256];
  int t = threadIdx.x;
  int s = (t < nb) ? part[t] : 0;
  sm[t] = s;
  __syncthreads();
  for (int off = 1; off < 256; off <<= 1) {
    int x = (t >= off) ? sm[t - off] : 0;
    __syncthreads();
    sm[t] += x;
    __syncthreads();
  }
  if (t < nb) part[t] = sm[t] - s;
}

__global__ __launch_bounds__(256) void k_add_off(int* __restrict__ rowptr, const int* __restrict__ part,
                                                 int n, int total) {
  int i = blockIdx.x * 256 + threadIdx.x;
  int s = gridDim.x * 256;
  for (; i < n; i += s) rowptr[i] += part[i >> 10];
  if (blockIdx.x == 0 && threadIdx.x == 0) rowptr[n] = total;
}

// ---- phase 3: atomic-free scatter via LDS cursors (slots pre-reserved) ----
__global__ __launch_bounds__(1024) void k_scatter2(const int* __restrict__ src, const int* __restrict__ dst,
                                                   const int* __restrict__ rp_f, const int* __restrict__ rp_m,
                                                   const int* __restrict__ cnt,
                                                   int* __restrict__ col_f, int* __restrict__ col_m,
                                                   int E, int NF, int NM) {
  __shared__ int cur[15104];
  int g = blockIdx.x & (NG - 1);
  int c = blockIdx.x >> 3;
  int t = threadIdx.x;
  int NFg = (NF + NG - 1) / NG, NMg = (NM + NG - 1) / NG;
  int loF = g * NFg, hiF = dmin(NF, loF + NFg);
  int loM = g * NMg, hiM = dmin(NM, loM + NMg);
  size_t K = (size_t)NF + NM;
  const int* cc = cnt + (size_t)c * K;
  for (int j = t; j < NFg; j += 1024) {
    int k = loF + j;
    if (k < hiF) cur[j] = rp_f[k] + cc[k];
  }
  for (int j = t; j < NMg; j += 1024) {
    int k = loM + j;
    if (k < hiM) cur[NFg + j] = rp_m[k] + cc[NF + k];
  }
  __syncthreads();
  int Epc = (E + NB - 1) / NB;
  int c0 = c * Epc, c1 = dmin(E, c0 + Epc);
  for (int i = c0 + t; i < c1; i += 1024) {
    int s = src[i], d = dst[i];
    if (s >= loF && s < hiF) {
      int p = atomicAdd(&cur[s - loF], 1);  // LDS atomic (CU-local, cheap)
      col_f[p] = d;
    }
    if (d >= loM && d < hiM) {
      int p = atomicAdd(&cur[NFg + (d - loM)], 1);
      col_m[p] = s;
    }
  }
}

// convert the 7 weight matrices we need to bf16, packed into one dst buffer
__global__ __launch_bounds__(256) void k_w2bf(const float* __restrict__ s0, const float* __restrict__ s1,
                                              const float* __restrict__ s2, const float* __restrict__ s3,
                                              const float* __restrict__ s4, const float* __restrict__ s5,
                                              const float* __restrict__ s6, u16* __restrict__ dst) {
  int i = blockIdx.x * 256 + threadIdx.x;  // grid = 416 blocks exactly
  const float* s; int off = i;
  if (i < 16384) { s = s0; }
  else if (i < 32768) { s = s1; off = i - 16384; }
  else if (i < 49152) { s = s2; off = i - 32768; }
  else if (i < 65536) { s = s3; off = i - 49152; }
  else if (i < 81920) { s = s4; off = i - 65536; }
  else if (i < 98304) { s = s5; off = i - 81920; }
  else { s = s6; off = i - 98304; }
  dst[i] = f2bf(s[off]);
}

// out[r][c] = relu(b[c] + sum_k W[c][k]*x[r][k]); W is [128][din]; din in {5,8}
__global__ __launch_bounds__(256) void k_proj(const float* __restrict__ x, const float* __restrict__ W,
                                              const float* __restrict__ b, u16* __restrict__ out,
                                              int n, int din) {
  __shared__ float Wls[128 * 9];
  __shared__ float bs[128];
  int t = threadIdx.x;
  int sw = din | 1;
  for (int i = t; i < 128 * din; i += 256) {
    int c = i / din, k = i - c * din;
    Wls[c * sw + k] = W[i];
  }
  for (int i = t; i < 128; i += 256) bs[i] = b[i];
  __syncthreads();
  int idx = blockIdx.x * 256 + t;
  int gs = gridDim.x * 256;
  for (; idx < n * 64; idx += gs) {
    int row = idx >> 6, cp = (idx & 63) * 2;
    float a0 = bs[cp], a1 = bs[cp + 1];
    const float* xr = x + (size_t)row * din;
    for (int k = 0; k < din; ++k) {
      float xv = xr[k];
      a0 += Wls[cp * sw + k] * xv;
      a1 += Wls[(cp + 1) * sw + k] * xv;
    }
    a0 = fmaxf(a0, 0.f);
    a1 = fmaxf(a1, 0.f);
    u32 pk = (u32)f2bf(a0) | ((u32)f2bf(a1) << 16);
    *(u32*)(out + (size_t)row * HDIM + cp) = pk;
  }
}

// one wave per dst node: out[d][:] = mean over neighbors of feat[idx][:] (bf16 rows)
__global__ __launch_bounds__(256) void k_agg(const u16* __restrict__ feat, const int* __restrict__ rowptr,
                                             const int* __restrict__ col, u16* __restrict__ out, int ndst) {
  int w = (blockIdx.x * 256 + threadIdx.x) >> 6;
  int lane = threadIdx.x & 63;
  if (w >= ndst) return;
  int s0 = rowptr[w], s1 = rowptr[w + 1];
  float a0 = 0.f, a1 = 0.f, b0 = 0.f, b1 = 0.f;
  int j = s0;
  for (; j + 3 < s1; j += 4) {
    int i0 = col[j], i1 = col[j + 1], i2 = col[j + 2], i3 = col[j + 3];
    u32 v0 = *(const u32*)(feat + (size_t)i0 * HDIM + lane * 2);
    u32 v1 = *(const u32*)(feat + (size_t)i1 * HDIM + lane * 2);
    u32 v2 = *(const u32*)(feat + (size_t)i2 * HDIM + lane * 2);
    u32 v3 = *(const u32*)(feat + (size_t)i3 * HDIM + lane * 2);
    a0 += bf2f((u16)v0) + bf2f((u16)v1);
    a1 += bf2f((u16)(v0 >> 16)) + bf2f((u16)(v1 >> 16));
    b0 += bf2f((u16)v2) + bf2f((u16)v3);
    b1 += bf2f((u16)(v2 >> 16)) + bf2f((u16)(v3 >> 16));
  }
  for (; j < s1; ++j) {
    u32 v = *(const u32*)(feat + (size_t)col[j] * HDIM + lane * 2);
    a0 += bf2f((u16)v);
    a1 += bf2f((u16)(v >> 16));
  }
  a0 += b0;
  a1 += b1;
  int deg = s1 - s0;
  float inv = deg > 0 ? 1.f / (float)deg : 0.f;
  u32 pk = (u32)f2bf(a0 * inv) | ((u32)f2bf(a1 * inv) << 16);
  *(u32*)(out + (size_t)w * HDIM + lane * 2) = pk;
}

// MFMA GEMM, swapped operands (A=W, B=X): acc[nt][r] = C[row0+lm][nt*16+cg+r].
// Each lane owns ONE output row and 4 consecutive cols per nt -> ushort4/float4
// vectorized epilogue (8B stores) instead of scalar u16 scatter.
// 32 rows per wave (two B-frags share each W A-frag): 64 MFMA / 40 loads.
__global__ __launch_bounds__(256) void k_ling(const u16* __restrict__ X1, const u16* __restrict__ W1,
                                              const u16* __restrict__ X2, const u16* __restrict__ W2,
                                              const u16* __restrict__ ADD, const float* __restrict__ bias,
                                              u16* __restrict__ out, int n, int do_relu) {
  int t = threadIdx.x;
  int w = t >> 6, lane = t & 63;
  int lm = lane & 15, lk = (lane >> 4) * 8;
  int cg = (lane >> 4) * 4;
  int row0 = blockIdx.x * 128 + w * 32;
  if (row0 >= n) return;
  int r0 = row0 + lm;       if (r0 >= n) r0 = n - 1;
  int r1 = row0 + 16 + lm;  if (r1 >= n) r1 = n - 1;
  f32x4 acc0[8], acc1[8];
  #pragma unroll
  for (int i = 0; i < 8; ++i) { acc0[i] = (f32x4){0.f,0.f,0.f,0.f}; acc1[i] = (f32x4){0.f,0.f,0.f,0.f}; }
  const u16* Xp = X1;
  const u16* Wp = W1;
  for (int p = 0; p < 2; ++p) {
    #pragma unroll
    for (int ks = 0; ks < 4; ++ks) {
      bf16x8 b0 = *(const bf16x8*)(Xp + (size_t)r0 * 128 + ks * 32 + lk);
      bf16x8 b1 = *(const bf16x8*)(Xp + (size_t)r1 * 128 + ks * 32 + lk);
      #pragma unroll
      for (int nt = 0; nt < 8; ++nt) {
        bf16x8 a = *(const bf16x8*)(Wp + (size_t)(nt * 16 + lm) * 128 + ks * 32 + lk);
        acc0[nt] = __builtin_amdgcn_mfma_f32_16x16x32_bf16(a, b0, acc0[nt], 0, 0, 0);
        acc1[nt] = __builtin_amdgcn_mfma_f32_16x16x32_bf16(a, b1, acc1[nt], 0, 0, 0);
      }
    }
    if (!X2) break;
    Xp = X2;
    Wp = W2;
  }
  #pragma unroll
  for (int half = 0; half < 2; ++half) {
    int m = row0 + half * 16 + lm;
    if (m >= n) break;
    f32x4* acc = half ? acc1 : acc0;
    #pragma unroll
    for (int nt = 0; nt < 8; ++nt) {
      int c = nt * 16 + cg;
      float v0 = acc[nt][0], v1 = acc[nt][1], v2 = acc[nt][2], v3 = acc[nt][3];
      if (bias) {
        float4 bv = *(const float4*)(bias + c);
        v0 += bv.x; v1 += bv.y; v2 += bv.z; v3 += bv.w;
      }
      if (ADD) {
        ushort4 av = *(const ushort4*)(ADD + (size_t)m * 128 + c);
        v0 += bf2f(av.x); v1 += bf2f(av.y); v2 += bf2f(av.z); v3 += bf2f(av.w);
      }
      if (do_relu) {
        v0 = fmaxf(v0, 0.f); v1 = fmaxf(v1, 0.f); v2 = fmaxf(v2, 0.f); v3 = fmaxf(v3, 0.f);
      }
      ushort4 pk;
      pk.x = f2bf(v0); pk.y = f2bf(v1); pk.z = f2bf(v2); pk.w = f2bf(v3);
      *(ushort4*)(out + (size_t)m * 128 + c) = pk;
    }
  }
}

// fused classifier, swapped operands: lane owns h[row0+lm][k] for k in
// {nt*16+cg+0..3}; GEMM2 = in-register FMAs + shfl_xor(16,32) reduce.
__global__ __launch_bounds__(256) void k_cls(const u16* __restrict__ f2, const u16* __restrict__ Wc1bf,
                                             const float* __restrict__ bc1, const float* __restrict__ Wc2,
                                             const float* __restrict__ bc2, float* __restrict__ out, int n) {
  int t = threadIdx.x;
  int w = t >> 6, lane = t & 63;
  int lm = lane & 15, lk = (lane >> 4) * 8;
  int cg = (lane >> 4) * 4;
  int row0 = blockIdx.x * 64 + w * 16;
  if (row0 >= n) return;
  int rB = row0 + lm;
  if (rB >= n) rB = n - 1;
  f32x4 acc[4];
  #pragma unroll
  for (int i = 0; i < 4; ++i) acc[i] = (f32x4){0.f, 0.f, 0.f, 0.f};
  #pragma unroll
  for (int ks = 0; ks < 4; ++ks) {
    bf16x8 b = *(const bf16x8*)(f2 + (size_t)rB * 128 + ks * 32 + lk);
    #pragma unroll
    for (int nt = 0; nt < 4; ++nt) {
      bf16x8 a = *(const bf16x8*)(Wc1bf + (size_t)(nt * 16 + lm) * 128 + ks * 32 + lk);
      acc[nt] = __builtin_amdgcn_mfma_f32_16x16x32_bf16(a, b, acc[nt], 0, 0, 0);
    }
  }
  float s0 = 0.f, s1 = 0.f;
  #pragma unroll
  for (int nt = 0; nt < 4; ++nt) {
    int k = nt * 16 + cg;
    float4 bv = *(const float4*)(bc1 + k);
    float4 w0 = *(const float4*)(Wc2 + k);
    float4 w1 = *(const float4*)(Wc2 + 64 + k);
    float h0 = fmaxf(acc[nt][0] + bv.x, 0.f);
    float h1 = fmaxf(acc[nt][1] + bv.y, 0.f);
    float h2 = fmaxf(acc[nt][2] + bv.z, 0.f);
    float h3 = fmaxf(acc[nt][3] + bv.w, 0.f);
    s0 += h0 * w0.x + h1 * w0.y + h2 * w0.z + h3 * w0.w;
    s1 += h0 * w1.x + h1 * w1.y + h2 * w1.z + h3 * w1.w;
  }
  s0 += __shfl_xor(s0, 16); s1 += __shfl_xor(s1, 16);
  s0 += __shfl_xor(s0, 32); s1 += __shfl_xor(s1, 32);
  int m = row0 + lm;
  if (lane < 16 && m < n) {
    out[(size_t)m * 2 + 0] = s0 + bc2[0];
    out[(size_t)m * 2 + 1] = s1 + bc2[1];
  }
}

static inline int imin(int a, int b) { return a < b ? a : b; }

extern "C" void kernel_launch(void* const* d_in, const int* in_sizes, int n_in,
                              void* d_out, int out_size, void* d_ws, size_t ws_size,
                              hipStream_t stream) {
  const float* x_fund = (const float*)d_in[0];
  const float* x_mgr  = (const float*)d_in[1];
  const int* fm_src   = (const int*)d_in[2];
  const int* fm_dst   = (const int*)d_in[3];
  const float* Wf = (const float*)d_in[4];
  const float* bfb = (const float*)d_in[5];
  const float* Wm = (const float*)d_in[6];
  const float* bm = (const float*)d_in[7];
  const float* Wl_fm0 = (const float*)d_in[8];
  const float* bl_fm0 = (const float*)d_in[9];
  const float* Wr_fm0 = (const float*)d_in[10];
  const float* Wl_mf0 = (const float*)d_in[11];
  const float* bl_mf0 = (const float*)d_in[12];
  const float* Wr_mf0 = (const float*)d_in[13];
  const float* Wl_mf1 = (const float*)d_in[17];
  const float* bl_mf1 = (const float*)d_in[18];
  const float* Wr_mf1 = (const float*)d_in[19];
  const float* Wc1 = (const float*)d_in[20];
  const float* bc1 = (const float*)d_in[21];
  const float* Wc2 = (const float*)d_in[22];
  const float* bc2 = (const float*)d_in[23];
  // (Wl_fm1/bl_fm1/Wr_fm1 at indices 14..16 are dead: m2 is deleted in the reference)

  int NF = in_sizes[0] / 8;
  int NM = in_sizes[1] / 5;
  int E  = in_sizes[2];
  int K  = NF + NM;

  char* ws = (char*)d_ws;
  size_t off = 0;
  auto alloc = [&](size_t bytes) -> char* {
    char* p = ws + off;
    off += (bytes + 255) & ~(size_t)255;
    return p;
  };
  u16* f_b   = (u16*)alloc((size_t)NF * HDIM * 2);
  u16* f1_b  = (u16*)alloc((size_t)NF * HDIM * 2);
  u16* f2_b  = (u16*)alloc((size_t)NF * HDIM * 2);
  u16* aggf  = (u16*)alloc((size_t)NF * HDIM * 2);
  u16* m_b   = (u16*)alloc((size_t)NM * HDIM * 2);
  u16* m1_b  = (u16*)alloc((size_t)NM * HDIM * 2);
  u16* t_b   = (u16*)alloc((size_t)NM * HDIM * 2);
  u16* aggm  = (u16*)alloc((size_t)NM * HDIM * 2);
  u16* wbf   = (u16*)alloc((size_t)106496 * 2);
  int* rp_f  = (int*)alloc((size_t)(NF + 1) * 4);
  int* rp_m  = (int*)alloc((size_t)(NM + 1) * 4);
  int* deg   = (int*)alloc((size_t)K * 4);
  int* col_f = (int*)alloc((size_t)E * 4);
  int* col_m = (int*)alloc((size_t)E * 4);
  int* cnt   = (int*)alloc((size_t)NB * K * 4);
  int* part_f = (int*)alloc(256 * 4);
  int* part_m = (int*)alloc(256 * 4);
  (void)ws_size; (void)n_in; (void)out_size;

  u16* Wlfm0b = wbf + 0;
  u16* Wrfm0b = wbf + 16384;
  u16* Wlmf0b = wbf + 32768;
  u16* Wrmf0b = wbf + 49152;
  u16* Wlmf1b = wbf + 65536;
  u16* Wrmf1b = wbf + 81920;
  u16* Wc1b   = wbf + 98304;

  int nch_f = (NF + 1023) / 1024;
  int nch_m = (NM + 1023) / 1024;

  // ---- weight conversion (bf16) ----
  k_w2bf<<<416, 256, 0, stream>>>(Wl_fm0, Wr_fm0, Wl_mf0, Wr_mf0, Wl_mf1, Wr_mf1, Wc1, wbf);

  // ---- atomic-free CSR build ----
  k_hist2<<<NG * NB, 1024, 0, stream>>>(fm_src, fm_dst, cnt, E, NF, NM);
  k_colscan<<<(K + 255) / 256, 256, 0, stream>>>(cnt, deg, K);
  k_scan_chunks<<<nch_f, 256, 0, stream>>>(deg, NF, rp_f, part_f);
  k_scan_chunks<<<nch_m, 256, 0, stream>>>(deg + NF, NM, rp_m, part_m);
  k_scan_part<<<1, 256, 0, stream>>>(part_f, nch_f);
  k_scan_part<<<1, 256, 0, stream>>>(part_m, nch_m);
  k_add_off<<<(NF + 255) / 256, 256, 0, stream>>>(rp_f, part_f, NF, E);
  k_add_off<<<(NM + 255) / 256, 256, 0, stream>>>(rp_m, part_m, NM, E);
  k_scatter2<<<NG * NB, 1024, 0, stream>>>(fm_src, fm_dst, rp_f, rp_m, cnt, col_f, col_m, E, NF, NM);

  // ---- input projections ----
  k_proj<<<imin((NF * 64 + 255) / 256, 4096), 256, 0, stream>>>(x_fund, Wf, bfb, f_b, NF, 8);
  k_proj<<<imin((NM * 64 + 255) / 256, 4096), 256, 0, stream>>>(x_mgr, Wm, bm, m_b, NM, 5);

  // ---- layer 0, fund->manager: m1 = relu(agg(f)@Wl + m@Wr + bl) ----
  k_agg<<<(NM + 3) / 4, 256, 0, stream>>>(f_b, rp_m, col_m, aggm, NM);
  k_ling<<<(NM + 127) / 128, 256, 0, stream>>>(aggm, Wlfm0b, m_b, Wrfm0b, nullptr, bl_fm0, m1_b, NM, 1);

  // ---- layer 0, manager->fund: f1 = relu(agg(m@Wl) + f@Wr + bl) ----
  k_ling<<<(NM + 127) / 128, 256, 0, stream>>>(m_b, Wlmf0b, nullptr, nullptr, nullptr, nullptr, t_b, NM, 0);
  k_agg<<<(NF + 3) / 4, 256, 0, stream>>>(t_b, rp_f, col_f, aggf, NF);
  k_ling<<<(NF + 127) / 128, 256, 0, stream>>>(f_b, Wrmf0b, nullptr, nullptr, aggf, bl_mf0, f1_b, NF, 1);

  // ---- layer 1, manager->fund only (m2 dead): f2 = relu(agg(m1@Wl) + f1@Wr + bl) ----
  k_ling<<<(NM + 127) / 128, 256, 0, stream>>>(m1_b, Wlmf1b, nullptr, nullptr, nullptr, nullptr, t_b, NM, 0);
  k_agg<<<(NF + 3) / 4, 256, 0, stream>>>(t_b, rp_f, col_f, aggf, NF);
  k_ling<<<(NF + 127) / 128, 256, 0, stream>>>(f1_b, Wrmf1b, nullptr, nullptr, aggf, bl_mf1, f2_b, NF, 1);

  // ---- classifier on fund nodes ----
  k_cls<<<(NF + 63) / 64, 256, 0, stream>>>(f2_b, Wc1b, bc1, Wc2, bc2, (float*)d_out, NF);
}